// Round 12
// baseline (67.657 us; speedup 1.0000x reference)
//
#include <hip/hip_runtime.h>
#include <hip/hip_fp16.h>

// ---------------------------------------------------------------------------
// Problem constants: B=16, T=2048, C=128, N=64, FFT length NF=4096
// ---------------------------------------------------------------------------

#define PAD(i) ((i) + ((i) >> 4))

using bf16x8 = __attribute__((ext_vector_type(8))) short;
using f32x4 = __attribute__((ext_vector_type(4))) float;
typedef unsigned short ushort_t;

static __device__ __forceinline__ float2 cmulf(float2 a, float2 b) {
  return make_float2(a.x * b.x - a.y * b.y, a.x * b.y + a.y * b.x);
}
static __device__ __forceinline__ float2 cadd(float2 a, float2 b) { return make_float2(a.x + b.x, a.y + b.y); }
static __device__ __forceinline__ float2 csub(float2 a, float2 b) { return make_float2(a.x - b.x, a.y - b.y); }
static __device__ __forceinline__ float2 cconj(float2 a) { return make_float2(a.x, -a.y); }
// tanh-form GELU via HW exp2/rcp (max |diff vs exact erf| ~3e-4 -> safe here).
static __device__ __forceinline__ float gelu1(float x) {
  float x2 = x * x;
  float z = x * fmaf(0.0356774081f, x2, 0.7978845608f);
  z = fminf(fmaxf(z, -15.0f), 15.0f);
  float e = __builtin_amdgcn_exp2f(z * 2.8853900817779268f);
  return x * e * __builtin_amdgcn_rcpf(e + 1.0f);
}
static __device__ __forceinline__ ushort_t f2bf(float f) {  // RNE f32->bf16
  unsigned int u = __float_as_uint(f);
  u += 0x7FFFu + ((u >> 16) & 1u);
  return (ushort_t)(u >> 16);
}
static __device__ __forceinline__ float bf2f(ushort_t u) {
  return __uint_as_float(((unsigned int)u) << 16);
}
// Hardware twiddles: v_sin/v_cos take input in REVOLUTIONS (D = sin(2*pi*S0)).
static __device__ __forceinline__ float2 twf(float rev) {  // e^{-2*pi*i*rev}
  return make_float2(__builtin_amdgcn_cosf(rev), -__builtin_amdgcn_sinf(rev));
}
static __device__ __forceinline__ float2 twi(float rev) {  // e^{+2*pi*i*rev}
  return make_float2(__builtin_amdgcn_cosf(rev), __builtin_amdgcn_sinf(rev));
}
// fp16-packed LDS exchange helpers (conv only): complex -> one 4B half2 word.
static __device__ __forceinline__ __half2 c2h(float2 v) { return __float22half2_rn(v); }
static __device__ __forceinline__ float2 h2c(__half2 h) {
  float2 f = __half22float2(h);
  return make_float2(f.x, f.y);
}

template <bool INV>
static __device__ __forceinline__ void bf4g(float2& a, float2& b, float2& c, float2& d, float2 w1) {
  float2 t0 = cadd(a, c), t1 = csub(a, c), t2 = cadd(b, d), t3 = csub(b, d);
  float2 w2 = cmulf(w1, w1), w3 = cmulf(w2, w1);
  float2 o0 = cadd(t0, t2);
  float2 o1 = cmulf(csub(t0, t2), w2);
  float2 o2, o3;
  if (!INV) {
    o2 = cmulf(make_float2(t1.x + t3.y, t1.y - t3.x), w1);
    o3 = cmulf(make_float2(t1.x - t3.y, t1.y + t3.x), w3);
  } else {
    o2 = cmulf(make_float2(t1.x - t3.y, t1.y + t3.x), w1);
    o3 = cmulf(make_float2(t1.x + t3.y, t1.y - t3.x), w3);
  }
  a = o0; b = o1; c = o2; d = o3;
}
static __device__ __forceinline__ void bf4f(float2& a, float2& b, float2& c, float2& d, float2 w1) {
  bf4g<false>(a, b, c, d, w1);
}
static __device__ __forceinline__ void bf4f1(float2& a, float2& b, float2& c, float2& d) {
  float2 t0 = cadd(a, c), t1 = csub(a, c), t2 = cadd(b, d), t3 = csub(b, d);
  a = cadd(t0, t2);
  b = csub(t0, t2);
  c = make_float2(t1.x + t3.y, t1.y - t3.x);
  d = make_float2(t1.x - t3.y, t1.y + t3.x);
}
static __device__ __forceinline__ void bf4f_z(float2 a, float2 b, float2 w1,
                                              float2& o0, float2& o1, float2& o2, float2& o3) {
  float2 w2 = cmulf(w1, w1), w3 = cmulf(w2, w1);
  o0 = cadd(a, b);
  o1 = cmulf(csub(a, b), w2);
  o2 = cmulf(make_float2(a.x + b.y, a.y - b.x), w1);
  o3 = cmulf(make_float2(a.x - b.y, a.y + b.x), w3);
}
template <bool INV>
static __device__ __forceinline__ void bf4h(float2& a, float2& b, float2& c, float2& d, float2 u1) {
  float2 u2 = cmulf(u1, u1);
  float2 tb = cmulf(b, u2), td = cmulf(d, u2);
  float2 a1 = cadd(a, tb), b1 = csub(a, tb), c1 = cadd(c, td), d1 = csub(c, td);
  float2 tc = cmulf(c1, u1), te = cmulf(d1, u1);
  a = cadd(a1, tc);
  c = csub(a1, tc);
  if (INV) {
    b = make_float2(b1.x - te.y, b1.y + te.x);
    d = make_float2(b1.x + te.y, b1.y - te.x);
  } else {
    b = make_float2(b1.x + te.y, b1.y - te.x);
    d = make_float2(b1.x - te.y, b1.y + te.x);
  }
}
static __device__ __forceinline__ void bf4i(float2& a, float2& b, float2& c, float2& d, float2 u1) {
  bf4h<true>(a, b, c, d, u1);
}
static __device__ __forceinline__ void bf4i1(float2& a, float2& b, float2& c, float2& d) {
  float2 a1 = cadd(a, b), b1 = csub(a, b), c1 = cadd(c, d), d1 = csub(c, d);
  a = cadd(a1, c1);
  c = csub(a1, c1);
  b = make_float2(b1.x - d1.y, b1.y + d1.x);
  d = make_float2(b1.x + d1.y, b1.y - d1.x);
}

#define W256R 0.9238795325112867f
#define W256I -0.3826834323650898f
#define W512R 0.7071067811865476f
#define W512I -0.7071067811865476f
#define W768R 0.3826834323650898f
#define W768I -0.9238795325112867f

// ---------------------------------------------------------------------------
// Kernel 1 (fused): blocks [0,1024): LayerNorm+transpose (B,T,C)->(B,C,T) bf16.
//                   blocks [1024,2048): at_roots Cauchy sums (1 root/thread).
// ---------------------------------------------------------------------------
__global__ __launch_bounds__(256) void k_ln_ar(
    const float* __restrict__ x, const float* __restrict__ gamma, const float* __restrict__ beta,
    ushort_t* __restrict__ y_bf,
    const float* __restrict__ Lr, const float* __restrict__ Li,
    const float* __restrict__ Pr, const float* __restrict__ Pi,
    const float* __restrict__ Br, const float* __restrict__ Bi,
    const float* __restrict__ Cr, const float* __restrict__ Ci,
    float2* __restrict__ arr) {
  __shared__ __align__(16) char sm[17536];
  const int tid = threadIdx.x;
  if (blockIdx.x < 1024) {
    // ---------------- LayerNorm + transpose ----------------
    float* tile = (float*)sm;              // [32*129]
    float* sg = (float*)(sm + 16512);      // [128]
    float* sb = (float*)(sm + 17024);      // [128]
    const int b = blockIdx.x >> 6;
    const int t0 = (blockIdx.x & 63) << 5;
    if (tid < 128) { sg[tid] = gamma[tid]; sb[tid] = beta[tid]; }
    const float4* __restrict__ xb4 = (const float4*)(x + ((size_t)b * 2048 + t0) * 128);
#pragma unroll
    for (int r = 0; r < 4; ++r) {
      int idx = tid + 256 * r;  // 32 t x 32 j
      int t = idx >> 5, j = idx & 31;
      float4 v4 = xb4[idx];
      float* dst = &tile[t * 129 + 4 * j];
      dst[0] = v4.x; dst[1] = v4.y; dst[2] = v4.z; dst[3] = v4.w;
    }
    __syncthreads();
    const int row = tid >> 3, sgp = tid & 7;
    float sum = 0.f, sq = 0.f;
#pragma unroll
    for (int i = 0; i < 16; ++i) {
      float v = tile[row * 129 + sgp * 16 + i];
      sum += v;
      sq += v * v;
    }
    sum += __shfl_xor(sum, 1); sq += __shfl_xor(sq, 1);
    sum += __shfl_xor(sum, 2); sq += __shfl_xor(sq, 2);
    sum += __shfl_xor(sum, 4); sq += __shfl_xor(sq, 4);
    float mean = sum * (1.0f / 128.0f);
    float var = sq * (1.0f / 128.0f) - mean * mean;
    float rstd = 1.0f / sqrtf(var + 1e-5f);
#pragma unroll
    for (int i = 0; i < 16; ++i) {
      int cc = sgp * 16 + i;
      float v = tile[row * 129 + cc];
      tile[row * 129 + cc] = (v - mean) * rstd * sg[cc] + sb[cc];
    }
    __syncthreads();
    ushort_t* __restrict__ yb = y_bf + (size_t)b * 128 * 2048 + t0;
#pragma unroll
    for (int r = 0; r < 4; ++r) {
      int idx = tid + 256 * r;  // 128 cc x 8 tl4
      int cc = idx >> 3, tl4 = (idx & 7) * 4;
      ushort4 o4;
      o4.x = f2bf(tile[(tl4 + 0) * 129 + cc]);
      o4.y = f2bf(tile[(tl4 + 1) * 129 + cc]);
      o4.z = f2bf(tile[(tl4 + 2) * 129 + cc]);
      o4.w = f2bf(tile[(tl4 + 3) * 129 + cc]);
      *(ushort4*)(yb + (size_t)cc * 2048 + tl4) = o4;
    }
  } else {
    // ---------------- at_roots (DPLR generating function) ----------------
    // NOTE: Omega must use the APPROXIMATE angle (sincosf of theta) exactly
    // like the JAX reference; exact trig makes 1+Omega==0 at l=1024 -> NaN.
    float2* sLam = (float2*)sm;
    float2* sv00 = sLam + 64;
    float2* sv01 = sLam + 128;
    float2* sv10 = sLam + 192;
    float2* sv11 = sLam + 256;
    const int id = blockIdx.x - 1024;  // [0,1024)
    const int c = id >> 3;
    const int l = ((id & 7) << 8) + tid;
    if (tid < 64) {
      int i = c * 64 + tid;
      float lr = fminf(Lr[i], 1e-4f), li = Li[i];
      float pr = Pr[i], pi = Pi[i];
      float br = Br[i], bi = Bi[i];
      float cr = Cr[i], ci = Ci[i];
      sLam[tid] = make_float2(lr, li);
      sv00[tid] = make_float2(cr * br + ci * bi, cr * bi - ci * br);
      sv01[tid] = make_float2(cr * pr + ci * pi, cr * pi - ci * pr);
      sv10[tid] = make_float2(pr * br + pi * bi, pr * bi - pi * br);
      sv11[tid] = make_float2(pr * pr + pi * pi, 0.0f);
    }
    __syncthreads();
    float theta = (-6.2831855f * (float)l) * (1.0f / 2048.0f);
    float om_i, om_r;
    sincosf(theta, &om_i, &om_r);
    float pr_ = 1.0f + om_r, pi_ = om_i;
    float mr_ = 1.0f - om_r, mi_ = -om_i;
    float invd = __builtin_amdgcn_rcpf(fmaf(pr_, pr_, pi_ * pi_));
    float gr = 200.0f * ((mr_ * pr_ + mi_ * pi_) * invd);
    float gi = 200.0f * ((mi_ * pr_ - mr_ * pi_) * invd);
    float c2r = 2.0f * pr_ * invd, c2i = -2.0f * pi_ * invd;
    float s00r = 0.f, s00i = 0.f, s01r = 0.f, s01i = 0.f;
    float s10r = 0.f, s10i = 0.f, s11r = 0.f, s11i = 0.f;
#pragma unroll 8
    for (int n = 0; n < 64; ++n) {
      float2 lam = sLam[n];
      float dr = gr - lam.x, di = gi - lam.y;
      float idn = __builtin_amdgcn_rcpf(fmaf(dr, dr, di * di));
      float ir = dr * idn, ii = -di * idn;
      float2 v;
      v = sv00[n]; s00r += v.x * ir - v.y * ii; s00i += v.x * ii + v.y * ir;
      v = sv01[n]; s01r += v.x * ir - v.y * ii; s01i += v.x * ii + v.y * ir;
      v = sv10[n]; s10r += v.x * ir - v.y * ii; s10i += v.x * ii + v.y * ir;
      v = sv11[n]; s11r += v.x * ir - v.y * ii; s11i += v.x * ii + v.y * ir;
    }
    float dr2 = 1.0f + s11r, di2 = s11i;
    float idn2 = __builtin_amdgcn_rcpf(fmaf(dr2, dr2, di2 * di2));
    float rr = dr2 * idn2, ri = -di2 * idn2;
    float t1r = s01r * rr - s01i * ri, t1i = s01r * ri + s01i * rr;
    float t2r = t1r * s10r - t1i * s10i, t2i = t1r * s10i + t1i * s10r;
    float fr = s00r - t2r, fi = s00i - t2i;
    arr[(size_t)c * 2048 + l] = make_float2(c2r * fr - c2i * fi, c2r * fi + c2i * fr);
  }
}

// ---------------------------------------------------------------------------
// Kernel 2: kf via even/odd-bin split. 512 threads/block, HW twiddles.
// ---------------------------------------------------------------------------
template <int Q, bool INV>
static __device__ __forceinline__ void kfs_dif(float2* s, int tid) {
  constexpr float SCR = (float)(2048 / (4 * Q)) * (1.0f / 2048.0f);  // revolutions
  int k = tid;  // [0,512)
  int j = k & (Q - 1);
  int i = ((k - j) << 2) + j;
  float2 w1 = INV ? twi((float)j * SCR) : twf((float)j * SCR);
  float2 a = s[PAD(i)], b = s[PAD(i + Q)], c2 = s[PAD(i + 2 * Q)], d = s[PAD(i + 3 * Q)];
  bf4g<INV>(a, b, c2, d, w1);
  s[PAD(i)] = a; s[PAD(i + Q)] = b; s[PAD(i + 2 * Q)] = c2; s[PAD(i + 3 * Q)] = d;
  __syncthreads();
}
template <int Q>
static __device__ __forceinline__ void kfs_dit(float2* s, int tid) {
  constexpr float SCR = (float)(2048 / (4 * Q)) * (1.0f / 2048.0f);
  int k = tid;
  int j = k & (Q - 1);
  int i = ((k - j) << 2) + j;
  float2 u1 = twf((float)j * SCR);
  float2 a = s[PAD(i)], b = s[PAD(i + Q)], c2 = s[PAD(i + 2 * Q)], d = s[PAD(i + 3 * Q)];
  bf4h<false>(a, b, c2, d, u1);
  s[PAD(i)] = a; s[PAD(i + Q)] = b; s[PAD(i + 2 * Q)] = c2; s[PAD(i + 3 * Q)] = d;
  __syncthreads();
}
static __device__ __forceinline__ void kfs_r2(float2* s, int tid) {
#pragma unroll
  for (int m = 0; m < 2; ++m) {
    int k = tid + 512 * m;  // [0,1024)
    int i = 2 * k;
    float2 a = s[PAD(i)], b = s[PAD(i + 1)];
    s[PAD(i)] = cadd(a, b);
    s[PAD(i + 1)] = csub(a, b);
  }
  __syncthreads();
}

__global__ __launch_bounds__(512) void k_kf(const float2* __restrict__ arr, float2* __restrict__ kf) {
  __shared__ float2 s[2176];
  const int tid = threadIdx.x;
  const int c = blockIdx.x;
  const float2* __restrict__ ac = arr + (size_t)c * 2048;
  float2* __restrict__ kfc = kf + (size_t)c * 4096;
#pragma unroll
  for (int m = 0; m < 4; ++m) {
    int q = tid + 512 * m;
    float2 aq = ac[q];
    s[PAD(q)] = aq;
    float2 am = ac[(2048 - q) & 2047];
    kfc[__brev((unsigned)q) >> 21] =
        make_float2((aq.x + am.x) * (0.5f / 4096.0f), (aq.y - am.y) * (0.5f / 4096.0f));
  }
  __syncthreads();
  kfs_dif<512, true>(s, tid);
  kfs_dif<128, true>(s, tid);
  kfs_dif<32, true>(s, tid);
  kfs_dif<8, true>(s, tid);
  kfs_dif<2, true>(s, tid);
  kfs_r2(s, tid);
#pragma unroll
  for (int m = 0; m < 4; ++m) {
    int p = tid + 512 * m;
    int t = (int)(__brev((unsigned)p) >> 21);
    float2 w = twf((float)t * (1.0f / 4096.0f));
    float kr = s[PAD(p)].x * (1.0f / 8388608.0f);
    s[PAD(p)] = make_float2(kr * w.x, kr * w.y);
  }
  __syncthreads();
  kfs_r2(s, tid);
  kfs_dit<2>(s, tid);
  kfs_dit<8>(s, tid);
  kfs_dit<32>(s, tid);
  kfs_dit<128>(s, tid);
  kfs_dit<512>(s, tid);
#pragma unroll
  for (int m = 0; m < 4; ++m) {
    int q = tid + 512 * m;
    kfc[2048 + (int)(__brev((unsigned)q) >> 21)] = s[PAD(q)];
  }
}

// ---------------------------------------------------------------------------
// Kernel 3: paired real FFT conv (y bf16), 3-level register FFT, HW twiddles;
// D*y folded into spectrum; tanh-GELU; fp16-packed LDS exchanges (17.4 KB
// instead of 34.8 KB -> ~2x occupancy); writes h as bf16 (B,C,T).
// ---------------------------------------------------------------------------
__global__ __launch_bounds__(256) void k_conv(const ushort_t* __restrict__ y_bf,
                                              const float2* __restrict__ kf,
                                              const float* __restrict__ D,
                                              ushort_t* __restrict__ h_bf) {
  __shared__ __half2 s[4352];
  const int tid = threadIdx.x;
  const int p = blockIdx.x;
  const int b = p >> 7, c = p & 127;
  const ushort_t* __restrict__ r1 = y_bf + (size_t)(b * 128 + c) * 2048;
  const ushort_t* __restrict__ r2 = y_bf + (size_t)((b + 8) * 128 + c) * 2048;
  ushort_t* __restrict__ hb1 = h_bf + (size_t)(b * 128 + c) * 2048;
  ushort_t* __restrict__ hb2 = h_bf + (size_t)((b + 8) * 128 + c) * 2048;

  const float2 K1 = make_float2(W256R, W256I);
  const float2 K2 = make_float2(W512R, W512I);
  const float2 K3 = make_float2(W768R, W768I);

  float2 v[16];
  // ---- forward phase A: Q=1024 (legs 2,3 zero), Q=256 ----
  {
    float2 ya[8];
#pragma unroll
    for (int e = 0; e < 8; ++e)
      ya[e] = make_float2(bf2f(r1[tid + 256 * e]), bf2f(r2[tid + 256 * e]));
    const float2 wt = twf((float)tid * (1.0f / 4096.0f));
    bf4f_z(ya[0], ya[4], wt,            v[0], v[4], v[8], v[12]);
    bf4f_z(ya[1], ya[5], cmulf(wt, K1), v[1], v[5], v[9], v[13]);
    bf4f_z(ya[2], ya[6], cmulf(wt, K2), v[2], v[6], v[10], v[14]);
    bf4f_z(ya[3], ya[7], cmulf(wt, K3), v[3], v[7], v[11], v[15]);
  }
  {
    const float2 wq = twf((float)tid * (1.0f / 1024.0f));
    bf4f(v[0], v[1], v[2], v[3], wq);
    bf4f(v[4], v[5], v[6], v[7], wq);
    bf4f(v[8], v[9], v[10], v[11], wq);
    bf4f(v[12], v[13], v[14], v[15], wq);
  }
  // ---- exchange 1: write A-pattern, read B-pattern ----
  {
    const int wb0 = tid + (tid >> 4);
#pragma unroll
    for (int e = 0; e < 16; ++e) s[272 * e + wb0] = c2h(v[e]);
  }
  __syncthreads();
  const int a_ = tid >> 4, b_ = tid & 15;
  const int rbB = 272 * a_ + b_;
#pragma unroll
  for (int e = 0; e < 16; ++e) v[e] = h2c(s[rbB + 17 * e]);
  // ---- forward phase B: Q=64, Q=16 ----
  {
    const float2 wb = twf((float)b_ * (1.0f / 256.0f));
    bf4f(v[0], v[4], v[8], v[12], wb);
    bf4f(v[1], v[5], v[9], v[13], cmulf(wb, K1));
    bf4f(v[2], v[6], v[10], v[14], cmulf(wb, K2));
    bf4f(v[3], v[7], v[11], v[15], cmulf(wb, K3));
  }
  {
    const float2 w16 = twf((float)b_ * (1.0f / 64.0f));
    bf4f(v[0], v[1], v[2], v[3], w16);
    bf4f(v[4], v[5], v[6], v[7], w16);
    bf4f(v[8], v[9], v[10], v[11], w16);
    bf4f(v[12], v[13], v[14], v[15], w16);
  }
  // ---- exchange 2 ----
#pragma unroll
  for (int e = 0; e < 16; ++e) s[rbB + 17 * e] = c2h(v[e]);
  __syncthreads();
#pragma unroll
  for (int e = 0; e < 16; ++e) v[e] = h2c(s[17 * tid + e]);
  // ---- forward phase C ----
  bf4f1(v[0], v[4], v[8], v[12]);
  bf4f(v[1], v[5], v[9], v[13], K1);
  bf4f(v[2], v[6], v[10], v[14], K2);
  bf4f(v[3], v[7], v[11], v[15], K3);
  bf4f1(v[0], v[1], v[2], v[3]);
  bf4f1(v[4], v[5], v[6], v[7]);
  bf4f1(v[8], v[9], v[10], v[11]);
  bf4f1(v[12], v[13], v[14], v[15]);
  // ---- spectral multiply with (K + D) (kf pre-scaled by 1/4096) ----
  {
    const float dsc = D[c] * (1.0f / 4096.0f);
    const float2* __restrict__ kfc = kf + (size_t)c * 4096 + 16 * tid;
#pragma unroll
    for (int e = 0; e < 16; ++e) {
      float2 kv = kfc[e];
      kv.x += dsc;
      v[e] = cmulf(v[e], kv);
    }
  }
  // ---- inverse phase C ----
  bf4i1(v[0], v[1], v[2], v[3]);
  bf4i1(v[4], v[5], v[6], v[7]);
  bf4i1(v[8], v[9], v[10], v[11]);
  bf4i1(v[12], v[13], v[14], v[15]);
  bf4i1(v[0], v[4], v[8], v[12]);
  bf4i(v[1], v[5], v[9], v[13], cconj(K1));
  bf4i(v[2], v[6], v[10], v[14], cconj(K2));
  bf4i(v[3], v[7], v[11], v[15], cconj(K3));
  // ---- exchange 3 ----
#pragma unroll
  for (int e = 0; e < 16; ++e) s[17 * tid + e] = c2h(v[e]);
  __syncthreads();
#pragma unroll
  for (int e = 0; e < 16; ++e) v[e] = h2c(s[rbB + 17 * e]);
  // ---- inverse phase B ----
  {
    const float2 w16c = twi((float)b_ * (1.0f / 64.0f));
    bf4i(v[0], v[1], v[2], v[3], w16c);
    bf4i(v[4], v[5], v[6], v[7], w16c);
    bf4i(v[8], v[9], v[10], v[11], w16c);
    bf4i(v[12], v[13], v[14], v[15], w16c);
  }
  {
    const float2 wbc = twi((float)b_ * (1.0f / 256.0f));
    bf4i(v[0], v[4], v[8], v[12], wbc);
    bf4i(v[1], v[5], v[9], v[13], cmulf(wbc, cconj(K1)));
    bf4i(v[2], v[6], v[10], v[14], cmulf(wbc, cconj(K2)));
    bf4i(v[3], v[7], v[11], v[15], cmulf(wbc, cconj(K3)));
  }
  // ---- exchange 4 ----
#pragma unroll
  for (int e = 0; e < 16; ++e) s[rbB + 17 * e] = c2h(v[e]);
  __syncthreads();
  {
    const int wb0 = tid + (tid >> 4);
#pragma unroll
    for (int e = 0; e < 16; ++e) v[e] = h2c(s[272 * e + wb0]);
  }
  // ---- inverse phase A: Q=256, then Q=1024 fused with GELU + bf16 store ----
  {
    const float2 wqc = twi((float)tid * (1.0f / 1024.0f));
    bf4i(v[0], v[1], v[2], v[3], wqc);
    bf4i(v[4], v[5], v[6], v[7], wqc);
    bf4i(v[8], v[9], v[10], v[11], wqc);
    bf4i(v[12], v[13], v[14], v[15], wqc);
  }
  const float2 wtc = twi((float)tid * (1.0f / 4096.0f));
  auto fin = [&](float2 va, float2 vb, float2 vc2, float2 vd, float2 u1, int e0) {
    float2 u2 = cmulf(u1, u1);
    float2 tb = cmulf(vb, u2), td = cmulf(vd, u2);
    float2 a1 = cadd(va, tb), b1 = csub(va, tb), c1 = cadd(vc2, td), d1 = csub(vc2, td);
    float2 tc = cmulf(c1, u1), te = cmulf(d1, u1);
    float2 oa = cadd(a1, tc);
    float2 ob = make_float2(b1.x - te.y, b1.y + te.x);
    int i0 = tid + 256 * e0;
    hb1[i0] = f2bf(gelu1(oa.x));
    hb2[i0] = f2bf(gelu1(oa.y));
    hb1[i0 + 1024] = f2bf(gelu1(ob.x));
    hb2[i0 + 1024] = f2bf(gelu1(ob.y));
  };
  fin(v[0], v[4], v[8], v[12], wtc, 0);
  fin(v[1], v[5], v[9], v[13], cmulf(wtc, cconj(K1)), 1);
  fin(v[2], v[6], v[10], v[14], cmulf(wtc, cconj(K2)), 2);
  fin(v[3], v[7], v[11], v[15], cmulf(wtc, cconj(K3)), 3);
}

// ---------------------------------------------------------------------------
// Kernel 4 (MFMA bf16): out[b,t,o] = sum_c h[b,c,t]*W[o,c] + b_out[o] + x[b,t,o]
// ---------------------------------------------------------------------------
__global__ __launch_bounds__(256) void k_out(const ushort_t* __restrict__ h_bf,
                                             const float* __restrict__ W,
                                             const float* __restrict__ bout,
                                             const float* __restrict__ x,
                                             float* __restrict__ out) {
  __shared__ __align__(16) char smem[52224];
  ushort_t* Wl = (ushort_t*)smem;                  // [128][136]
  ushort_t* hl = (ushort_t*)(smem + 34816);        // [64][136]
  const int tid = threadIdx.x;
  const int b = blockIdx.x >> 5;
  const int t0 = (blockIdx.x & 31) << 6;

  // stage W (fp32 -> bf16, swizzled: col' = ((cb ^ (o&15))<<3) + (c&7))
  {
    const float4* __restrict__ W4 = (const float4*)W;
#pragma unroll
    for (int r = 0; r < 16; ++r) {
      int idx = tid + 256 * r;  // 128 o x 32 j
      int o = idx >> 5, j = idx & 31;
      float4 w4 = W4[o * 32 + j];
      int sc = (((j >> 1) ^ (o & 15)) << 3) + 4 * (j & 1);
      ushort4 u;
      u.x = f2bf(w4.x); u.y = f2bf(w4.y); u.z = f2bf(w4.z); u.w = f2bf(w4.w);
      *(ushort4*)&Wl[o * 136 + sc] = u;
    }
  }
  // stage h tile (bf16 global (b,c,t) -> LDS [t][c] swizzled)
  {
#pragma unroll
    for (int r = 0; r < 8; ++r) {
      int idx = tid + 256 * r;  // 128 c x 16 t4
      int cc = idx >> 4, t4 = (idx & 15) * 4;
      ushort4 hv = *(const ushort4*)&h_bf[((size_t)(b * 128 + cc)) * 2048 + t0 + t4];
      int cb = cc >> 3, clo = cc & 7;
#pragma unroll
      for (int i = 0; i < 4; ++i) {
        int t = t4 + i;
        hl[t * 136 + (((cb ^ (t & 15)) << 3) + clo)] = ((const ushort_t*)&hv)[i];
      }
    }
  }
  __syncthreads();

  const int l = tid & 63;
  const int w = tid >> 6;
  const int tl = l & 15;
  const int g = l >> 4;
  f32x4 acc[8];
#pragma unroll
  for (int i = 0; i < 8; ++i) acc[i] = (f32x4){0.f, 0.f, 0.f, 0.f};

#pragma unroll
  for (int ks = 0; ks < 4; ++ks) {
    int cb = ks * 4 + g;
    int col = ((cb ^ tl) << 3);
    bf16x8 bfrag = *(const bf16x8*)&hl[(16 * w + tl) * 136 + col];
#pragma unroll
    for (int ot = 0; ot < 8; ++ot) {
      bf16x8 afrag = *(const bf16x8*)&Wl[(ot * 16 + tl) * 136 + col];
      acc[ot] = __builtin_amdgcn_mfma_f32_16x16x32_bf16(afrag, bfrag, acc[ot], 0, 0, 0);
    }
  }
  // direct epilogue: acc[ot][r] = out[o=16ot+4g+r][t=16w+tl]
  const int t = t0 + 16 * w + tl;
  const size_t rowoff = ((size_t)b * 2048 + t) * 128;
#pragma unroll
  for (int ot = 0; ot < 8; ++ot) {
    int o = ot * 16 + g * 4;
    float4 xv = *(const float4*)&x[rowoff + o];
    float4 bo4 = *(const float4*)&bout[o];
    float4 v;
    v.x = acc[ot][0] + bo4.x + xv.x;
    v.y = acc[ot][1] + bo4.y + xv.y;
    v.z = acc[ot][2] + bo4.z + xv.z;
    v.w = acc[ot][3] + bo4.w + xv.w;
    *(float4*)&out[rowoff + o] = v;
  }
}

// ---------------------------------------------------------------------------

extern "C" void kernel_launch(void* const* d_in, const int* in_sizes, int n_in,
                              void* d_out, int out_size, void* d_ws, size_t ws_size,
                              hipStream_t stream) {
  (void)in_sizes; (void)n_in; (void)out_size; (void)ws_size;
  const float* x  = (const float*)d_in[0];
  const float* g  = (const float*)d_in[1];
  const float* be = (const float*)d_in[2];
  const float* Lr = (const float*)d_in[3];
  const float* Li = (const float*)d_in[4];
  const float* Pr = (const float*)d_in[5];
  const float* Pi = (const float*)d_in[6];
  const float* Br = (const float*)d_in[7];
  const float* Bi = (const float*)d_in[8];
  const float* Cr = (const float*)d_in[9];
  const float* Ci = (const float*)d_in[10];
  const float* D  = (const float*)d_in[11];
  const float* W  = (const float*)d_in[12];
  const float* bo = (const float*)d_in[13];
  float* out = (float*)d_out;

  char* ws = (char*)d_ws;
  ushort_t* y_bf = (ushort_t*)ws;                 //  8 MiB: y bf16 (B,C,T)
  float2*   arr  = (float2*)(ws + (16u << 20));   //  2 MiB: at_roots (C,L)
  float2*   kfb  = (float2*)(ws + (18u << 20));   //  4 MiB: kernel spectrum
  ushort_t* h_bf = (ushort_t*)(ws + (22u << 20)); //  8 MiB: h bf16 (B,C,T)

  hipLaunchKernelGGL(k_ln_ar, dim3(2048), dim3(256), 0, stream,
                     x, g, be, y_bf, Lr, Li, Pr, Pi, Br, Bi, Cr, Ci, arr);
  hipLaunchKernelGGL(k_kf,   dim3(128),  dim3(512), 0, stream, arr, kfb);
  hipLaunchKernelGGL(k_conv, dim3(1024), dim3(256), 0, stream, y_bf, kfb, D, h_bf);
  hipLaunchKernelGGL(k_out,  dim3(512),  dim3(256), 0, stream, h_bf, W, bo, x, out);
}

// Round 13
// 66.723 us; speedup vs baseline: 1.0140x; 1.0140x over previous
//
#include <hip/hip_runtime.h>

// ---------------------------------------------------------------------------
// Problem constants: B=16, T=2048, C=128, N=64, FFT length NF=4096
// ---------------------------------------------------------------------------

#define PAD(i) ((i) + ((i) >> 4))

using bf16x8 = __attribute__((ext_vector_type(8))) short;
using f32x4 = __attribute__((ext_vector_type(4))) float;
typedef unsigned short ushort_t;

static __device__ __forceinline__ float2 cmulf(float2 a, float2 b) {
  return make_float2(a.x * b.x - a.y * b.y, a.x * b.y + a.y * b.x);
}
static __device__ __forceinline__ float2 cadd(float2 a, float2 b) { return make_float2(a.x + b.x, a.y + b.y); }
static __device__ __forceinline__ float2 csub(float2 a, float2 b) { return make_float2(a.x - b.x, a.y - b.y); }
static __device__ __forceinline__ float2 cconj(float2 a) { return make_float2(a.x, -a.y); }
// tanh-form GELU via HW exp2/rcp (max |diff vs exact erf| ~3e-4 -> safe here).
static __device__ __forceinline__ float gelu1(float x) {
  float x2 = x * x;
  float z = x * fmaf(0.0356774081f, x2, 0.7978845608f);
  z = fminf(fmaxf(z, -15.0f), 15.0f);
  float e = __builtin_amdgcn_exp2f(z * 2.8853900817779268f);
  return x * e * __builtin_amdgcn_rcpf(e + 1.0f);
}
static __device__ __forceinline__ ushort_t f2bf(float f) {  // RNE f32->bf16
  unsigned int u = __float_as_uint(f);
  u += 0x7FFFu + ((u >> 16) & 1u);
  return (ushort_t)(u >> 16);
}
static __device__ __forceinline__ float bf2f(ushort_t u) {
  return __uint_as_float(((unsigned int)u) << 16);
}
// Hardware twiddles: v_sin/v_cos take input in REVOLUTIONS (D = sin(2*pi*S0)).
static __device__ __forceinline__ float2 twf(float rev) {  // e^{-2*pi*i*rev}
  return make_float2(__builtin_amdgcn_cosf(rev), -__builtin_amdgcn_sinf(rev));
}
static __device__ __forceinline__ float2 twi(float rev) {  // e^{+2*pi*i*rev}
  return make_float2(__builtin_amdgcn_cosf(rev), __builtin_amdgcn_sinf(rev));
}

template <bool INV>
static __device__ __forceinline__ void bf4g(float2& a, float2& b, float2& c, float2& d, float2 w1) {
  float2 t0 = cadd(a, c), t1 = csub(a, c), t2 = cadd(b, d), t3 = csub(b, d);
  float2 w2 = cmulf(w1, w1), w3 = cmulf(w2, w1);
  float2 o0 = cadd(t0, t2);
  float2 o1 = cmulf(csub(t0, t2), w2);
  float2 o2, o3;
  if (!INV) {
    o2 = cmulf(make_float2(t1.x + t3.y, t1.y - t3.x), w1);
    o3 = cmulf(make_float2(t1.x - t3.y, t1.y + t3.x), w3);
  } else {
    o2 = cmulf(make_float2(t1.x - t3.y, t1.y + t3.x), w1);
    o3 = cmulf(make_float2(t1.x + t3.y, t1.y - t3.x), w3);
  }
  a = o0; b = o1; c = o2; d = o3;
}
static __device__ __forceinline__ void bf4f(float2& a, float2& b, float2& c, float2& d, float2 w1) {
  bf4g<false>(a, b, c, d, w1);
}
// forward DIF butterfly with precomputed twiddle powers (shared-w1 groups)
static __device__ __forceinline__ void bf4f3(float2& a, float2& b, float2& c, float2& d,
                                             float2 w1, float2 w2, float2 w3) {
  float2 t0 = cadd(a, c), t1 = csub(a, c), t2 = cadd(b, d), t3 = csub(b, d);
  a = cadd(t0, t2);
  b = cmulf(csub(t0, t2), w2);
  c = cmulf(make_float2(t1.x + t3.y, t1.y - t3.x), w1);
  d = cmulf(make_float2(t1.x - t3.y, t1.y + t3.x), w3);
}
static __device__ __forceinline__ void bf4f1(float2& a, float2& b, float2& c, float2& d) {
  float2 t0 = cadd(a, c), t1 = csub(a, c), t2 = cadd(b, d), t3 = csub(b, d);
  a = cadd(t0, t2);
  b = csub(t0, t2);
  c = make_float2(t1.x + t3.y, t1.y - t3.x);
  d = make_float2(t1.x - t3.y, t1.y + t3.x);
}
static __device__ __forceinline__ void bf4f_z(float2 a, float2 b, float2 w1,
                                              float2& o0, float2& o1, float2& o2, float2& o3) {
  float2 w2 = cmulf(w1, w1), w3 = cmulf(w2, w1);
  o0 = cadd(a, b);
  o1 = cmulf(csub(a, b), w2);
  o2 = cmulf(make_float2(a.x + b.y, a.y - b.x), w1);
  o3 = cmulf(make_float2(a.x - b.y, a.y + b.x), w3);
}
template <bool INV>
static __device__ __forceinline__ void bf4h(float2& a, float2& b, float2& c, float2& d, float2 u1) {
  float2 u2 = cmulf(u1, u1);
  float2 tb = cmulf(b, u2), td = cmulf(d, u2);
  float2 a1 = cadd(a, tb), b1 = csub(a, tb), c1 = cadd(c, td), d1 = csub(c, td);
  float2 tc = cmulf(c1, u1), te = cmulf(d1, u1);
  a = cadd(a1, tc);
  c = csub(a1, tc);
  if (INV) {
    b = make_float2(b1.x - te.y, b1.y + te.x);
    d = make_float2(b1.x + te.y, b1.y - te.x);
  } else {
    b = make_float2(b1.x + te.y, b1.y - te.x);
    d = make_float2(b1.x - te.y, b1.y + te.x);
  }
}
static __device__ __forceinline__ void bf4i(float2& a, float2& b, float2& c, float2& d, float2 u1) {
  bf4h<true>(a, b, c, d, u1);
}
// inverse DIT butterfly with precomputed u2 (shared-u1 groups)
static __device__ __forceinline__ void bf4i3(float2& a, float2& b, float2& c, float2& d,
                                             float2 u1, float2 u2) {
  float2 tb = cmulf(b, u2), td = cmulf(d, u2);
  float2 a1 = cadd(a, tb), b1 = csub(a, tb), c1 = cadd(c, td), d1 = csub(c, td);
  float2 tc = cmulf(c1, u1), te = cmulf(d1, u1);
  a = cadd(a1, tc);
  c = csub(a1, tc);
  b = make_float2(b1.x - te.y, b1.y + te.x);
  d = make_float2(b1.x + te.y, b1.y - te.x);
}
static __device__ __forceinline__ void bf4i1(float2& a, float2& b, float2& c, float2& d) {
  float2 a1 = cadd(a, b), b1 = csub(a, b), c1 = cadd(c, d), d1 = csub(c, d);
  a = cadd(a1, c1);
  c = csub(a1, c1);
  b = make_float2(b1.x - d1.y, b1.y + d1.x);
  d = make_float2(b1.x + d1.y, b1.y - d1.x);
}

#define W256R 0.9238795325112867f
#define W256I -0.3826834323650898f
#define W512R 0.7071067811865476f
#define W512I -0.7071067811865476f
#define W768R 0.3826834323650898f
#define W768I -0.9238795325112867f

// ---------------------------------------------------------------------------
// Kernel 1 (fused): blocks [0,1024): LayerNorm+transpose (B,T,C)->(B,C,T) bf16.
//                   blocks [1024,2048): at_roots Cauchy sums (1 root/thread).
//                   block 2048: W fp32 -> bf16 pre-conversion (for k_out).
// ---------------------------------------------------------------------------
__global__ __launch_bounds__(256) void k_ln_ar(
    const float* __restrict__ x, const float* __restrict__ gamma, const float* __restrict__ beta,
    ushort_t* __restrict__ y_bf,
    const float* __restrict__ Lr, const float* __restrict__ Li,
    const float* __restrict__ Pr, const float* __restrict__ Pi,
    const float* __restrict__ Br, const float* __restrict__ Bi,
    const float* __restrict__ Cr, const float* __restrict__ Ci,
    float2* __restrict__ arr,
    const float* __restrict__ W, ushort_t* __restrict__ w_bf) {
  __shared__ __align__(16) char sm[17536];
  const int tid = threadIdx.x;
  if (blockIdx.x < 1024) {
    // ---------------- LayerNorm + transpose ----------------
    float* tile = (float*)sm;              // [32*129]
    float* sg = (float*)(sm + 16512);      // [128]
    float* sb = (float*)(sm + 17024);      // [128]
    const int b = blockIdx.x >> 6;
    const int t0 = (blockIdx.x & 63) << 5;
    if (tid < 128) { sg[tid] = gamma[tid]; sb[tid] = beta[tid]; }
    const float4* __restrict__ xb4 = (const float4*)(x + ((size_t)b * 2048 + t0) * 128);
#pragma unroll
    for (int r = 0; r < 4; ++r) {
      int idx = tid + 256 * r;  // 32 t x 32 j
      int t = idx >> 5, j = idx & 31;
      float4 v4 = xb4[idx];
      float* dst = &tile[t * 129 + 4 * j];
      dst[0] = v4.x; dst[1] = v4.y; dst[2] = v4.z; dst[3] = v4.w;
    }
    __syncthreads();
    const int row = tid >> 3, sgp = tid & 7;
    float sum = 0.f, sq = 0.f;
#pragma unroll
    for (int i = 0; i < 16; ++i) {
      float v = tile[row * 129 + sgp * 16 + i];
      sum += v;
      sq += v * v;
    }
    sum += __shfl_xor(sum, 1); sq += __shfl_xor(sq, 1);
    sum += __shfl_xor(sum, 2); sq += __shfl_xor(sq, 2);
    sum += __shfl_xor(sum, 4); sq += __shfl_xor(sq, 4);
    float mean = sum * (1.0f / 128.0f);
    float var = sq * (1.0f / 128.0f) - mean * mean;
    float rstd = 1.0f / sqrtf(var + 1e-5f);
#pragma unroll
    for (int i = 0; i < 16; ++i) {
      int cc = sgp * 16 + i;
      float v = tile[row * 129 + cc];
      tile[row * 129 + cc] = (v - mean) * rstd * sg[cc] + sb[cc];
    }
    __syncthreads();
    ushort_t* __restrict__ yb = y_bf + (size_t)b * 128 * 2048 + t0;
#pragma unroll
    for (int r = 0; r < 4; ++r) {
      int idx = tid + 256 * r;  // 128 cc x 8 tl4
      int cc = idx >> 3, tl4 = (idx & 7) * 4;
      ushort4 o4;
      o4.x = f2bf(tile[(tl4 + 0) * 129 + cc]);
      o4.y = f2bf(tile[(tl4 + 1) * 129 + cc]);
      o4.z = f2bf(tile[(tl4 + 2) * 129 + cc]);
      o4.w = f2bf(tile[(tl4 + 3) * 129 + cc]);
      *(ushort4*)(yb + (size_t)cc * 2048 + tl4) = o4;
    }
  } else if (blockIdx.x < 2048) {
    // ---------------- at_roots (DPLR generating function) ----------------
    // NOTE: Omega must use the APPROXIMATE angle (sincosf of theta) exactly
    // like the JAX reference; exact trig makes 1+Omega==0 at l=1024 -> NaN.
    float2* sLam = (float2*)sm;
    float2* sv00 = sLam + 64;
    float2* sv01 = sLam + 128;
    float2* sv10 = sLam + 192;
    float2* sv11 = sLam + 256;
    const int id = blockIdx.x - 1024;  // [0,1024)
    const int c = id >> 3;
    const int l = ((id & 7) << 8) + tid;
    if (tid < 64) {
      int i = c * 64 + tid;
      float lr = fminf(Lr[i], 1e-4f), li = Li[i];
      float pr = Pr[i], pi = Pi[i];
      float br = Br[i], bi = Bi[i];
      float cr = Cr[i], ci = Ci[i];
      sLam[tid] = make_float2(lr, li);
      sv00[tid] = make_float2(cr * br + ci * bi, cr * bi - ci * br);
      sv01[tid] = make_float2(cr * pr + ci * pi, cr * pi - ci * pr);
      sv10[tid] = make_float2(pr * br + pi * bi, pr * bi - pi * br);
      sv11[tid] = make_float2(pr * pr + pi * pi, 0.0f);
    }
    __syncthreads();
    float theta = (-6.2831855f * (float)l) * (1.0f / 2048.0f);
    float om_i, om_r;
    sincosf(theta, &om_i, &om_r);
    float pr_ = 1.0f + om_r, pi_ = om_i;
    float mr_ = 1.0f - om_r, mi_ = -om_i;
    float invd = __builtin_amdgcn_rcpf(fmaf(pr_, pr_, pi_ * pi_));
    float gr = 200.0f * ((mr_ * pr_ + mi_ * pi_) * invd);
    float gi = 200.0f * ((mi_ * pr_ - mr_ * pi_) * invd);
    float c2r = 2.0f * pr_ * invd, c2i = -2.0f * pi_ * invd;
    float s00r = 0.f, s00i = 0.f, s01r = 0.f, s01i = 0.f;
    float s10r = 0.f, s10i = 0.f, s11r = 0.f, s11i = 0.f;
#pragma unroll 8
    for (int n = 0; n < 64; ++n) {
      float2 lam = sLam[n];
      float dr = gr - lam.x, di = gi - lam.y;
      float idn = __builtin_amdgcn_rcpf(fmaf(dr, dr, di * di));
      float ir = dr * idn, ii = -di * idn;
      float2 v;
      v = sv00[n]; s00r += v.x * ir - v.y * ii; s00i += v.x * ii + v.y * ir;
      v = sv01[n]; s01r += v.x * ir - v.y * ii; s01i += v.x * ii + v.y * ir;
      v = sv10[n]; s10r += v.x * ir - v.y * ii; s10i += v.x * ii + v.y * ir;
      v = sv11[n]; s11r += v.x * ir - v.y * ii; s11i += v.x * ii + v.y * ir;
    }
    float dr2 = 1.0f + s11r, di2 = s11i;
    float idn2 = __builtin_amdgcn_rcpf(fmaf(dr2, dr2, di2 * di2));
    float rr = dr2 * idn2, ri = -di2 * idn2;
    float t1r = s01r * rr - s01i * ri, t1i = s01r * ri + s01i * rr;
    float t2r = t1r * s10r - t1i * s10i, t2i = t1r * s10i + t1i * s10r;
    float fr = s00r - t2r, fi = s00i - t2i;
    arr[(size_t)c * 2048 + l] = make_float2(c2r * fr - c2i * fi, c2r * fi + c2i * fr);
  } else {
    // ---------------- W fp32 -> bf16 (once; consumed by k_out) ----------------
    const float4* __restrict__ W4 = (const float4*)W;
    ushort4* __restrict__ Wb4 = (ushort4*)w_bf;
#pragma unroll
    for (int m = 0; m < 16; ++m) {
      int idx = tid + 256 * m;  // [0,4096) float4s
      float4 w4 = W4[idx];
      ushort4 u;
      u.x = f2bf(w4.x); u.y = f2bf(w4.y); u.z = f2bf(w4.z); u.w = f2bf(w4.w);
      Wb4[idx] = u;
    }
  }
}

// ---------------------------------------------------------------------------
// Kernel 2: kf via even/odd-bin split. 512 threads/block, HW twiddles.
// ---------------------------------------------------------------------------
template <int Q, bool INV>
static __device__ __forceinline__ void kfs_dif(float2* s, int tid) {
  constexpr float SCR = (float)(2048 / (4 * Q)) * (1.0f / 2048.0f);  // revolutions
  int k = tid;  // [0,512)
  int j = k & (Q - 1);
  int i = ((k - j) << 2) + j;
  float2 w1 = INV ? twi((float)j * SCR) : twf((float)j * SCR);
  float2 a = s[PAD(i)], b = s[PAD(i + Q)], c2 = s[PAD(i + 2 * Q)], d = s[PAD(i + 3 * Q)];
  bf4g<INV>(a, b, c2, d, w1);
  s[PAD(i)] = a; s[PAD(i + Q)] = b; s[PAD(i + 2 * Q)] = c2; s[PAD(i + 3 * Q)] = d;
  __syncthreads();
}
template <int Q>
static __device__ __forceinline__ void kfs_dit(float2* s, int tid) {
  constexpr float SCR = (float)(2048 / (4 * Q)) * (1.0f / 2048.0f);
  int k = tid;
  int j = k & (Q - 1);
  int i = ((k - j) << 2) + j;
  float2 u1 = twf((float)j * SCR);
  float2 a = s[PAD(i)], b = s[PAD(i + Q)], c2 = s[PAD(i + 2 * Q)], d = s[PAD(i + 3 * Q)];
  bf4h<false>(a, b, c2, d, u1);
  s[PAD(i)] = a; s[PAD(i + Q)] = b; s[PAD(i + 2 * Q)] = c2; s[PAD(i + 3 * Q)] = d;
  __syncthreads();
}
static __device__ __forceinline__ void kfs_r2(float2* s, int tid) {
#pragma unroll
  for (int m = 0; m < 2; ++m) {
    int k = tid + 512 * m;  // [0,1024)
    int i = 2 * k;
    float2 a = s[PAD(i)], b = s[PAD(i + 1)];
    s[PAD(i)] = cadd(a, b);
    s[PAD(i + 1)] = csub(a, b);
  }
  __syncthreads();
}

__global__ __launch_bounds__(512) void k_kf(const float2* __restrict__ arr, float2* __restrict__ kf) {
  __shared__ float2 s[2176];
  const int tid = threadIdx.x;
  const int c = blockIdx.x;
  const float2* __restrict__ ac = arr + (size_t)c * 2048;
  float2* __restrict__ kfc = kf + (size_t)c * 4096;
#pragma unroll
  for (int m = 0; m < 4; ++m) {
    int q = tid + 512 * m;
    float2 aq = ac[q];
    s[PAD(q)] = aq;
    float2 am = ac[(2048 - q) & 2047];
    kfc[__brev((unsigned)q) >> 21] =
        make_float2((aq.x + am.x) * (0.5f / 4096.0f), (aq.y - am.y) * (0.5f / 4096.0f));
  }
  __syncthreads();
  kfs_dif<512, true>(s, tid);
  kfs_dif<128, true>(s, tid);
  kfs_dif<32, true>(s, tid);
  kfs_dif<8, true>(s, tid);
  kfs_dif<2, true>(s, tid);
  kfs_r2(s, tid);
#pragma unroll
  for (int m = 0; m < 4; ++m) {
    int p = tid + 512 * m;
    int t = (int)(__brev((unsigned)p) >> 21);
    float2 w = twf((float)t * (1.0f / 4096.0f));
    float kr = s[PAD(p)].x * (1.0f / 8388608.0f);
    s[PAD(p)] = make_float2(kr * w.x, kr * w.y);
  }
  __syncthreads();
  kfs_r2(s, tid);
  kfs_dit<2>(s, tid);
  kfs_dit<8>(s, tid);
  kfs_dit<32>(s, tid);
  kfs_dit<128>(s, tid);
  kfs_dit<512>(s, tid);
#pragma unroll
  for (int m = 0; m < 4; ++m) {
    int q = tid + 512 * m;
    kfc[2048 + (int)(__brev((unsigned)q) >> 21)] = s[PAD(q)];
  }
}

// ---------------------------------------------------------------------------
// Kernel 3: paired real FFT conv (y bf16), 3-level register FFT, HW twiddles;
// shared twiddle powers hoisted; D*y folded into spectrum; tanh-GELU;
// writes h as bf16 (B,C,T). (float2 LDS — R11 config, empirically best.)
// ---------------------------------------------------------------------------
__global__ __launch_bounds__(256) void k_conv(const ushort_t* __restrict__ y_bf,
                                              const float2* __restrict__ kf,
                                              const float* __restrict__ D,
                                              ushort_t* __restrict__ h_bf) {
  __shared__ float2 s[4352];
  const int tid = threadIdx.x;
  const int p = blockIdx.x;
  const int b = p >> 7, c = p & 127;
  const ushort_t* __restrict__ r1 = y_bf + (size_t)(b * 128 + c) * 2048;
  const ushort_t* __restrict__ r2 = y_bf + (size_t)((b + 8) * 128 + c) * 2048;
  ushort_t* __restrict__ hb1 = h_bf + (size_t)(b * 128 + c) * 2048;
  ushort_t* __restrict__ hb2 = h_bf + (size_t)((b + 8) * 128 + c) * 2048;

  const float2 K1 = make_float2(W256R, W256I);
  const float2 K2 = make_float2(W512R, W512I);
  const float2 K3 = make_float2(W768R, W768I);

  float2 v[16];
  // ---- forward phase A: Q=1024 (legs 2,3 zero), Q=256 ----
  {
    float2 ya[8];
#pragma unroll
    for (int e = 0; e < 8; ++e)
      ya[e] = make_float2(bf2f(r1[tid + 256 * e]), bf2f(r2[tid + 256 * e]));
    const float2 wt = twf((float)tid * (1.0f / 4096.0f));
    bf4f_z(ya[0], ya[4], wt,            v[0], v[4], v[8], v[12]);
    bf4f_z(ya[1], ya[5], cmulf(wt, K1), v[1], v[5], v[9], v[13]);
    bf4f_z(ya[2], ya[6], cmulf(wt, K2), v[2], v[6], v[10], v[14]);
    bf4f_z(ya[3], ya[7], cmulf(wt, K3), v[3], v[7], v[11], v[15]);
  }
  {
    const float2 wq = twf((float)tid * (1.0f / 1024.0f));
    const float2 wq2 = cmulf(wq, wq), wq3 = cmulf(wq2, wq);
    bf4f3(v[0], v[1], v[2], v[3], wq, wq2, wq3);
    bf4f3(v[4], v[5], v[6], v[7], wq, wq2, wq3);
    bf4f3(v[8], v[9], v[10], v[11], wq, wq2, wq3);
    bf4f3(v[12], v[13], v[14], v[15], wq, wq2, wq3);
  }
  // ---- exchange 1: write A-pattern, read B-pattern ----
  {
    const int wb0 = tid + (tid >> 4);
#pragma unroll
    for (int e = 0; e < 16; ++e) s[272 * e + wb0] = v[e];
  }
  __syncthreads();
  const int a_ = tid >> 4, b_ = tid & 15;
  const int rbB = 272 * a_ + b_;
#pragma unroll
  for (int e = 0; e < 16; ++e) v[e] = s[rbB + 17 * e];
  // ---- forward phase B: Q=64, Q=16 ----
  {
    const float2 wb = twf((float)b_ * (1.0f / 256.0f));
    bf4f(v[0], v[4], v[8], v[12], wb);
    bf4f(v[1], v[5], v[9], v[13], cmulf(wb, K1));
    bf4f(v[2], v[6], v[10], v[14], cmulf(wb, K2));
    bf4f(v[3], v[7], v[11], v[15], cmulf(wb, K3));
  }
  {
    const float2 w16 = twf((float)b_ * (1.0f / 64.0f));
    const float2 w162 = cmulf(w16, w16), w163 = cmulf(w162, w16);
    bf4f3(v[0], v[1], v[2], v[3], w16, w162, w163);
    bf4f3(v[4], v[5], v[6], v[7], w16, w162, w163);
    bf4f3(v[8], v[9], v[10], v[11], w16, w162, w163);
    bf4f3(v[12], v[13], v[14], v[15], w16, w162, w163);
  }
  // ---- exchange 2 ----
#pragma unroll
  for (int e = 0; e < 16; ++e) s[rbB + 17 * e] = v[e];
  __syncthreads();
#pragma unroll
  for (int e = 0; e < 16; ++e) v[e] = s[17 * tid + e];
  // ---- forward phase C ----
  bf4f1(v[0], v[4], v[8], v[12]);
  bf4f(v[1], v[5], v[9], v[13], K1);
  bf4f(v[2], v[6], v[10], v[14], K2);
  bf4f(v[3], v[7], v[11], v[15], K3);
  bf4f1(v[0], v[1], v[2], v[3]);
  bf4f1(v[4], v[5], v[6], v[7]);
  bf4f1(v[8], v[9], v[10], v[11]);
  bf4f1(v[12], v[13], v[14], v[15]);
  // ---- spectral multiply with (K + D) (kf pre-scaled by 1/4096) ----
  {
    const float dsc = D[c] * (1.0f / 4096.0f);
    const float2* __restrict__ kfc = kf + (size_t)c * 4096 + 16 * tid;
#pragma unroll
    for (int e = 0; e < 16; ++e) {
      float2 kv = kfc[e];
      kv.x += dsc;
      v[e] = cmulf(v[e], kv);
    }
  }
  // ---- inverse phase C ----
  bf4i1(v[0], v[1], v[2], v[3]);
  bf4i1(v[4], v[5], v[6], v[7]);
  bf4i1(v[8], v[9], v[10], v[11]);
  bf4i1(v[12], v[13], v[14], v[15]);
  bf4i1(v[0], v[4], v[8], v[12]);
  bf4i(v[1], v[5], v[9], v[13], cconj(K1));
  bf4i(v[2], v[6], v[10], v[14], cconj(K2));
  bf4i(v[3], v[7], v[11], v[15], cconj(K3));
  // ---- exchange 3 ----
#pragma unroll
  for (int e = 0; e < 16; ++e) s[17 * tid + e] = v[e];
  __syncthreads();
#pragma unroll
  for (int e = 0; e < 16; ++e) v[e] = s[rbB + 17 * e];
  // ---- inverse phase B ----
  {
    const float2 w16c = twi((float)b_ * (1.0f / 64.0f));
    const float2 w16c2 = cmulf(w16c, w16c);
    bf4i3(v[0], v[1], v[2], v[3], w16c, w16c2);
    bf4i3(v[4], v[5], v[6], v[7], w16c, w16c2);
    bf4i3(v[8], v[9], v[10], v[11], w16c, w16c2);
    bf4i3(v[12], v[13], v[14], v[15], w16c, w16c2);
  }
  {
    const float2 wbc = twi((float)b_ * (1.0f / 256.0f));
    bf4i(v[0], v[4], v[8], v[12], wbc);
    bf4i(v[1], v[5], v[9], v[13], cmulf(wbc, cconj(K1)));
    bf4i(v[2], v[6], v[10], v[14], cmulf(wbc, cconj(K2)));
    bf4i(v[3], v[7], v[11], v[15], cmulf(wbc, cconj(K3)));
  }
  // ---- exchange 4 ----
#pragma unroll
  for (int e = 0; e < 16; ++e) s[rbB + 17 * e] = v[e];
  __syncthreads();
  {
    const int wb0 = tid + (tid >> 4);
#pragma unroll
    for (int e = 0; e < 16; ++e) v[e] = s[272 * e + wb0];
  }
  // ---- inverse phase A: Q=256, then Q=1024 fused with GELU + bf16 store ----
  {
    const float2 wqc = twi((float)tid * (1.0f / 1024.0f));
    const float2 wqc2 = cmulf(wqc, wqc);
    bf4i3(v[0], v[1], v[2], v[3], wqc, wqc2);
    bf4i3(v[4], v[5], v[6], v[7], wqc, wqc2);
    bf4i3(v[8], v[9], v[10], v[11], wqc, wqc2);
    bf4i3(v[12], v[13], v[14], v[15], wqc, wqc2);
  }
  const float2 wtc = twi((float)tid * (1.0f / 4096.0f));
  auto fin = [&](float2 va, float2 vb, float2 vc2, float2 vd, float2 u1, int e0) {
    float2 u2 = cmulf(u1, u1);
    float2 tb = cmulf(vb, u2), td = cmulf(vd, u2);
    float2 a1 = cadd(va, tb), b1 = csub(va, tb), c1 = cadd(vc2, td), d1 = csub(vc2, td);
    float2 tc = cmulf(c1, u1), te = cmulf(d1, u1);
    float2 oa = cadd(a1, tc);
    float2 ob = make_float2(b1.x - te.y, b1.y + te.x);
    int i0 = tid + 256 * e0;
    hb1[i0] = f2bf(gelu1(oa.x));
    hb2[i0] = f2bf(gelu1(oa.y));
    hb1[i0 + 1024] = f2bf(gelu1(ob.x));
    hb2[i0 + 1024] = f2bf(gelu1(ob.y));
  };
  fin(v[0], v[4], v[8], v[12], wtc, 0);
  fin(v[1], v[5], v[9], v[13], cmulf(wtc, cconj(K1)), 1);
  fin(v[2], v[6], v[10], v[14], cmulf(wtc, cconj(K2)), 2);
  fin(v[3], v[7], v[11], v[15], cmulf(wtc, cconj(K3)), 3);
}

// ---------------------------------------------------------------------------
// Kernel 4 (MFMA bf16): out[b,t,o] = sum_c h[b,c,t]*W[o,c] + b_out[o] + x[b,t,o]
// W staged from pre-converted bf16 (w_bf, written by k_ln_ar block 2048).
// ---------------------------------------------------------------------------
__global__ __launch_bounds__(256) void k_out(const ushort_t* __restrict__ h_bf,
                                             const ushort_t* __restrict__ w_bf,
                                             const float* __restrict__ bout,
                                             const float* __restrict__ x,
                                             float* __restrict__ out) {
  __shared__ __align__(16) char smem[52224];
  ushort_t* Wl = (ushort_t*)smem;                  // [128][136]
  ushort_t* hl = (ushort_t*)(smem + 34816);        // [64][136]
  const int tid = threadIdx.x;
  const int b = blockIdx.x >> 5;
  const int t0 = (blockIdx.x & 31) << 6;

  // stage W (bf16, swizzled: col' = ((cb ^ (o&15))<<3) + (c&7))
  {
    const ushort4* __restrict__ Wb4 = (const ushort4*)w_bf;
#pragma unroll
    for (int r = 0; r < 16; ++r) {
      int idx = tid + 256 * r;  // 128 o x 32 j
      int o = idx >> 5, j = idx & 31;
      ushort4 u = Wb4[o * 32 + j];
      int sc = (((j >> 1) ^ (o & 15)) << 3) + 4 * (j & 1);
      *(ushort4*)&Wl[o * 136 + sc] = u;
    }
  }
  // stage h tile (bf16 global (b,c,t) -> LDS [t][c] swizzled)
  {
#pragma unroll
    for (int r = 0; r < 8; ++r) {
      int idx = tid + 256 * r;  // 128 c x 16 t4
      int cc = idx >> 4, t4 = (idx & 15) * 4;
      ushort4 hv = *(const ushort4*)&h_bf[((size_t)(b * 128 + cc)) * 2048 + t0 + t4];
      int cb = cc >> 3, clo = cc & 7;
#pragma unroll
      for (int i = 0; i < 4; ++i) {
        int t = t4 + i;
        hl[t * 136 + (((cb ^ (t & 15)) << 3) + clo)] = ((const ushort_t*)&hv)[i];
      }
    }
  }
  __syncthreads();

  const int l = tid & 63;
  const int w = tid >> 6;
  const int tl = l & 15;
  const int g = l >> 4;
  f32x4 acc[8];
#pragma unroll
  for (int i = 0; i < 8; ++i) acc[i] = (f32x4){0.f, 0.f, 0.f, 0.f};

#pragma unroll
  for (int ks = 0; ks < 4; ++ks) {
    int cb = ks * 4 + g;
    int col = ((cb ^ tl) << 3);
    bf16x8 bfrag = *(const bf16x8*)&hl[(16 * w + tl) * 136 + col];
#pragma unroll
    for (int ot = 0; ot < 8; ++ot) {
      bf16x8 afrag = *(const bf16x8*)&Wl[(ot * 16 + tl) * 136 + col];
      acc[ot] = __builtin_amdgcn_mfma_f32_16x16x32_bf16(afrag, bfrag, acc[ot], 0, 0, 0);
    }
  }
  // direct epilogue: acc[ot][r] = out[o=16ot+4g+r][t=16w+tl]
  const int t = t0 + 16 * w + tl;
  const size_t rowoff = ((size_t)b * 2048 + t) * 128;
#pragma unroll
  for (int ot = 0; ot < 8; ++ot) {
    int o = ot * 16 + g * 4;
    float4 xv = *(const float4*)&x[rowoff + o];
    float4 bo4 = *(const float4*)&bout[o];
    float4 v;
    v.x = acc[ot][0] + bo4.x + xv.x;
    v.y = acc[ot][1] + bo4.y + xv.y;
    v.z = acc[ot][2] + bo4.z + xv.z;
    v.w = acc[ot][3] + bo4.w + xv.w;
    *(float4*)&out[rowoff + o] = v;
  }
}

// ---------------------------------------------------------------------------

extern "C" void kernel_launch(void* const* d_in, const int* in_sizes, int n_in,
                              void* d_out, int out_size, void* d_ws, size_t ws_size,
                              hipStream_t stream) {
  (void)in_sizes; (void)n_in; (void)out_size; (void)ws_size;
  const float* x  = (const float*)d_in[0];
  const float* g  = (const float*)d_in[1];
  const float* be = (const float*)d_in[2];
  const float* Lr = (const float*)d_in[3];
  const float* Li = (const float*)d_in[4];
  const float* Pr = (const float*)d_in[5];
  const float* Pi = (const float*)d_in[6];
  const float* Br = (const float*)d_in[7];
  const float* Bi = (const float*)d_in[8];
  const float* Cr = (const float*)d_in[9];
  const float* Ci = (const float*)d_in[10];
  const float* D  = (const float*)d_in[11];
  const float* W  = (const float*)d_in[12];
  const float* bo = (const float*)d_in[13];
  float* out = (float*)d_out;

  char* ws = (char*)d_ws;
  ushort_t* y_bf = (ushort_t*)ws;                 //  8 MiB: y bf16 (B,C,T)
  float2*   arr  = (float2*)(ws + (16u << 20));   //  2 MiB: at_roots (C,L)
  float2*   kfb  = (float2*)(ws + (18u << 20));   //  4 MiB: kernel spectrum
  ushort_t* h_bf = (ushort_t*)(ws + (22u << 20)); //  8 MiB: h bf16 (B,C,T)
  ushort_t* w_bf = (ushort_t*)(ws + (30u << 20)); // 32 KiB: W bf16

  hipLaunchKernelGGL(k_ln_ar, dim3(2049), dim3(256), 0, stream,
                     x, g, be, y_bf, Lr, Li, Pr, Pi, Br, Bi, Cr, Ci, arr, W, w_bf);
  hipLaunchKernelGGL(k_kf,   dim3(128),  dim3(512), 0, stream, arr, kfb);
  hipLaunchKernelGGL(k_conv, dim3(1024), dim3(256), 0, stream, y_bf, kfb, D, h_bf);
  hipLaunchKernelGGL(k_out,  dim3(512),  dim3(256), 0, stream, h_bf, w_bf, bo, x, out);
}

// Round 14
// 66.127 us; speedup vs baseline: 1.0231x; 1.0090x over previous
//
#include <hip/hip_runtime.h>

// ---------------------------------------------------------------------------
// Problem constants: B=16, T=2048, C=128, N=64, FFT length NF=4096
// ---------------------------------------------------------------------------

#define PAD(i) ((i) + ((i) >> 4))

using bf16x8 = __attribute__((ext_vector_type(8))) short;
using f32x4 = __attribute__((ext_vector_type(4))) float;
typedef unsigned short ushort_t;

static __device__ __forceinline__ float2 cmulf(float2 a, float2 b) {
  return make_float2(a.x * b.x - a.y * b.y, a.x * b.y + a.y * b.x);
}
static __device__ __forceinline__ float2 cadd(float2 a, float2 b) { return make_float2(a.x + b.x, a.y + b.y); }
static __device__ __forceinline__ float2 csub(float2 a, float2 b) { return make_float2(a.x - b.x, a.y - b.y); }
static __device__ __forceinline__ float2 cconj(float2 a) { return make_float2(a.x, -a.y); }
// tanh-form GELU via HW exp2/rcp (max |diff vs exact erf| ~3e-4 -> safe here).
static __device__ __forceinline__ float gelu1(float x) {
  float x2 = x * x;
  float z = x * fmaf(0.0356774081f, x2, 0.7978845608f);
  z = fminf(fmaxf(z, -15.0f), 15.0f);
  float e = __builtin_amdgcn_exp2f(z * 2.8853900817779268f);
  return x * e * __builtin_amdgcn_rcpf(e + 1.0f);
}
static __device__ __forceinline__ ushort_t f2bf(float f) {  // RNE f32->bf16
  unsigned int u = __float_as_uint(f);
  u += 0x7FFFu + ((u >> 16) & 1u);
  return (ushort_t)(u >> 16);
}
static __device__ __forceinline__ float bf2f(ushort_t u) {
  return __uint_as_float(((unsigned int)u) << 16);
}
// Hardware twiddles: v_sin/v_cos take input in REVOLUTIONS (D = sin(2*pi*S0)).
static __device__ __forceinline__ float2 twf(float rev) {  // e^{-2*pi*i*rev}
  return make_float2(__builtin_amdgcn_cosf(rev), -__builtin_amdgcn_sinf(rev));
}
static __device__ __forceinline__ float2 twi(float rev) {  // e^{+2*pi*i*rev}
  return make_float2(__builtin_amdgcn_cosf(rev), __builtin_amdgcn_sinf(rev));
}

template <bool INV>
static __device__ __forceinline__ void bf4g(float2& a, float2& b, float2& c, float2& d, float2 w1) {
  float2 t0 = cadd(a, c), t1 = csub(a, c), t2 = cadd(b, d), t3 = csub(b, d);
  float2 w2 = cmulf(w1, w1), w3 = cmulf(w2, w1);
  float2 o0 = cadd(t0, t2);
  float2 o1 = cmulf(csub(t0, t2), w2);
  float2 o2, o3;
  if (!INV) {
    o2 = cmulf(make_float2(t1.x + t3.y, t1.y - t3.x), w1);
    o3 = cmulf(make_float2(t1.x - t3.y, t1.y + t3.x), w3);
  } else {
    o2 = cmulf(make_float2(t1.x - t3.y, t1.y + t3.x), w1);
    o3 = cmulf(make_float2(t1.x + t3.y, t1.y - t3.x), w3);
  }
  a = o0; b = o1; c = o2; d = o3;
}
static __device__ __forceinline__ void bf4f(float2& a, float2& b, float2& c, float2& d, float2 w1) {
  bf4g<false>(a, b, c, d, w1);
}
// forward DIF butterfly with precomputed twiddle powers (shared-w1 groups)
static __device__ __forceinline__ void bf4f3(float2& a, float2& b, float2& c, float2& d,
                                             float2 w1, float2 w2, float2 w3) {
  float2 t0 = cadd(a, c), t1 = csub(a, c), t2 = cadd(b, d), t3 = csub(b, d);
  a = cadd(t0, t2);
  b = cmulf(csub(t0, t2), w2);
  c = cmulf(make_float2(t1.x + t3.y, t1.y - t3.x), w1);
  d = cmulf(make_float2(t1.x - t3.y, t1.y + t3.x), w3);
}
static __device__ __forceinline__ void bf4f1(float2& a, float2& b, float2& c, float2& d) {
  float2 t0 = cadd(a, c), t1 = csub(a, c), t2 = cadd(b, d), t3 = csub(b, d);
  a = cadd(t0, t2);
  b = csub(t0, t2);
  c = make_float2(t1.x + t3.y, t1.y - t3.x);
  d = make_float2(t1.x - t3.y, t1.y + t3.x);
}
static __device__ __forceinline__ void bf4f_z(float2 a, float2 b, float2 w1,
                                              float2& o0, float2& o1, float2& o2, float2& o3) {
  float2 w2 = cmulf(w1, w1), w3 = cmulf(w2, w1);
  o0 = cadd(a, b);
  o1 = cmulf(csub(a, b), w2);
  o2 = cmulf(make_float2(a.x + b.y, a.y - b.x), w1);
  o3 = cmulf(make_float2(a.x - b.y, a.y + b.x), w3);
}
template <bool INV>
static __device__ __forceinline__ void bf4h(float2& a, float2& b, float2& c, float2& d, float2 u1) {
  float2 u2 = cmulf(u1, u1);
  float2 tb = cmulf(b, u2), td = cmulf(d, u2);
  float2 a1 = cadd(a, tb), b1 = csub(a, tb), c1 = cadd(c, td), d1 = csub(c, td);
  float2 tc = cmulf(c1, u1), te = cmulf(d1, u1);
  a = cadd(a1, tc);
  c = csub(a1, tc);
  if (INV) {
    b = make_float2(b1.x - te.y, b1.y + te.x);
    d = make_float2(b1.x + te.y, b1.y - te.x);
  } else {
    b = make_float2(b1.x + te.y, b1.y - te.x);
    d = make_float2(b1.x - te.y, b1.y + te.x);
  }
}
static __device__ __forceinline__ void bf4i(float2& a, float2& b, float2& c, float2& d, float2 u1) {
  bf4h<true>(a, b, c, d, u1);
}
// inverse DIT butterfly with precomputed u2 (shared-u1 groups)
static __device__ __forceinline__ void bf4i3(float2& a, float2& b, float2& c, float2& d,
                                             float2 u1, float2 u2) {
  float2 tb = cmulf(b, u2), td = cmulf(d, u2);
  float2 a1 = cadd(a, tb), b1 = csub(a, tb), c1 = cadd(c, td), d1 = csub(c, td);
  float2 tc = cmulf(c1, u1), te = cmulf(d1, u1);
  a = cadd(a1, tc);
  c = csub(a1, tc);
  b = make_float2(b1.x - te.y, b1.y + te.x);
  d = make_float2(b1.x + te.y, b1.y - te.x);
}
static __device__ __forceinline__ void bf4i1(float2& a, float2& b, float2& c, float2& d) {
  float2 a1 = cadd(a, b), b1 = csub(a, b), c1 = cadd(c, d), d1 = csub(c, d);
  a = cadd(a1, c1);
  c = csub(a1, c1);
  b = make_float2(b1.x - d1.y, b1.y + d1.x);
  d = make_float2(b1.x + d1.y, b1.y - d1.x);
}

#define W256R 0.9238795325112867f
#define W256I -0.3826834323650898f
#define W512R 0.7071067811865476f
#define W512I -0.7071067811865476f
#define W768R 0.3826834323650898f
#define W768I -0.9238795325112867f

// ---------------------------------------------------------------------------
// Kernel 1 (fused): blocks [0,1024): LayerNorm+transpose (B,T,C)->(B,C,T) bf16.
//                   blocks [1024,2048): at_roots Cauchy sums (1 root/thread).
//                   block 2048: W fp32 -> bf16 pre-conversion (for k_out).
// ---------------------------------------------------------------------------
__global__ __launch_bounds__(256) void k_ln_ar(
    const float* __restrict__ x, const float* __restrict__ gamma, const float* __restrict__ beta,
    ushort_t* __restrict__ y_bf,
    const float* __restrict__ Lr, const float* __restrict__ Li,
    const float* __restrict__ Pr, const float* __restrict__ Pi,
    const float* __restrict__ Br, const float* __restrict__ Bi,
    const float* __restrict__ Cr, const float* __restrict__ Ci,
    float2* __restrict__ arr,
    const float* __restrict__ W, ushort_t* __restrict__ w_bf) {
  __shared__ __align__(16) char sm[17536];
  const int tid = threadIdx.x;
  if (blockIdx.x < 1024) {
    // ---------------- LayerNorm + transpose ----------------
    float* tile = (float*)sm;              // [32*129]
    float* sg = (float*)(sm + 16512);      // [128]
    float* sb = (float*)(sm + 17024);      // [128]
    const int b = blockIdx.x >> 6;
    const int t0 = (blockIdx.x & 63) << 5;
    if (tid < 128) { sg[tid] = gamma[tid]; sb[tid] = beta[tid]; }
    const float4* __restrict__ xb4 = (const float4*)(x + ((size_t)b * 2048 + t0) * 128);
#pragma unroll
    for (int r = 0; r < 4; ++r) {
      int idx = tid + 256 * r;  // 32 t x 32 j
      int t = idx >> 5, j = idx & 31;
      float4 v4 = xb4[idx];
      float* dst = &tile[t * 129 + 4 * j];
      dst[0] = v4.x; dst[1] = v4.y; dst[2] = v4.z; dst[3] = v4.w;
    }
    __syncthreads();
    const int row = tid >> 3, sgp = tid & 7;
    float sum = 0.f, sq = 0.f;
#pragma unroll
    for (int i = 0; i < 16; ++i) {
      float v = tile[row * 129 + sgp * 16 + i];
      sum += v;
      sq += v * v;
    }
    sum += __shfl_xor(sum, 1); sq += __shfl_xor(sq, 1);
    sum += __shfl_xor(sum, 2); sq += __shfl_xor(sq, 2);
    sum += __shfl_xor(sum, 4); sq += __shfl_xor(sq, 4);
    float mean = sum * (1.0f / 128.0f);
    float var = sq * (1.0f / 128.0f) - mean * mean;
    float rstd = 1.0f / sqrtf(var + 1e-5f);
#pragma unroll
    for (int i = 0; i < 16; ++i) {
      int cc = sgp * 16 + i;
      float v = tile[row * 129 + cc];
      tile[row * 129 + cc] = (v - mean) * rstd * sg[cc] + sb[cc];
    }
    __syncthreads();
    ushort_t* __restrict__ yb = y_bf + (size_t)b * 128 * 2048 + t0;
#pragma unroll
    for (int r = 0; r < 4; ++r) {
      int idx = tid + 256 * r;  // 128 cc x 8 tl4
      int cc = idx >> 3, tl4 = (idx & 7) * 4;
      ushort4 o4;
      o4.x = f2bf(tile[(tl4 + 0) * 129 + cc]);
      o4.y = f2bf(tile[(tl4 + 1) * 129 + cc]);
      o4.z = f2bf(tile[(tl4 + 2) * 129 + cc]);
      o4.w = f2bf(tile[(tl4 + 3) * 129 + cc]);
      *(ushort4*)(yb + (size_t)cc * 2048 + tl4) = o4;
    }
  } else if (blockIdx.x < 2048) {
    // ---------------- at_roots (DPLR generating function) ----------------
    // NOTE: Omega must use the APPROXIMATE angle (sincosf of theta) exactly
    // like the JAX reference; exact trig makes 1+Omega==0 at l=1024 -> NaN.
    float2* sLam = (float2*)sm;
    float2* sv00 = sLam + 64;
    float2* sv01 = sLam + 128;
    float2* sv10 = sLam + 192;
    float2* sv11 = sLam + 256;
    const int id = blockIdx.x - 1024;  // [0,1024)
    const int c = id >> 3;
    const int l = ((id & 7) << 8) + tid;
    if (tid < 64) {
      int i = c * 64 + tid;
      float lr = fminf(Lr[i], 1e-4f), li = Li[i];
      float pr = Pr[i], pi = Pi[i];
      float br = Br[i], bi = Bi[i];
      float cr = Cr[i], ci = Ci[i];
      sLam[tid] = make_float2(lr, li);
      sv00[tid] = make_float2(cr * br + ci * bi, cr * bi - ci * br);
      sv01[tid] = make_float2(cr * pr + ci * pi, cr * pi - ci * pr);
      sv10[tid] = make_float2(pr * br + pi * bi, pr * bi - pi * br);
      sv11[tid] = make_float2(pr * pr + pi * pi, 0.0f);
    }
    __syncthreads();
    float theta = (-6.2831855f * (float)l) * (1.0f / 2048.0f);
    float om_i, om_r;
    sincosf(theta, &om_i, &om_r);
    float pr_ = 1.0f + om_r, pi_ = om_i;
    float mr_ = 1.0f - om_r, mi_ = -om_i;
    float invd = __builtin_amdgcn_rcpf(fmaf(pr_, pr_, pi_ * pi_));
    float gr = 200.0f * ((mr_ * pr_ + mi_ * pi_) * invd);
    float gi = 200.0f * ((mi_ * pr_ - mr_ * pi_) * invd);
    float c2r = 2.0f * pr_ * invd, c2i = -2.0f * pi_ * invd;
    float s00r = 0.f, s00i = 0.f, s01r = 0.f, s01i = 0.f;
    float s10r = 0.f, s10i = 0.f, s11r = 0.f, s11i = 0.f;
#pragma unroll 8
    for (int n = 0; n < 64; ++n) {
      float2 lam = sLam[n];
      float dr = gr - lam.x, di = gi - lam.y;
      float idn = __builtin_amdgcn_rcpf(fmaf(dr, dr, di * di));
      float ir = dr * idn, ii = -di * idn;
      float2 v;
      v = sv00[n]; s00r += v.x * ir - v.y * ii; s00i += v.x * ii + v.y * ir;
      v = sv01[n]; s01r += v.x * ir - v.y * ii; s01i += v.x * ii + v.y * ir;
      v = sv10[n]; s10r += v.x * ir - v.y * ii; s10i += v.x * ii + v.y * ir;
      v = sv11[n]; s11r += v.x * ir - v.y * ii; s11i += v.x * ii + v.y * ir;
    }
    float dr2 = 1.0f + s11r, di2 = s11i;
    float idn2 = __builtin_amdgcn_rcpf(fmaf(dr2, dr2, di2 * di2));
    float rr = dr2 * idn2, ri = -di2 * idn2;
    float t1r = s01r * rr - s01i * ri, t1i = s01r * ri + s01i * rr;
    float t2r = t1r * s10r - t1i * s10i, t2i = t1r * s10i + t1i * s10r;
    float fr = s00r - t2r, fi = s00i - t2i;
    arr[(size_t)c * 2048 + l] = make_float2(c2r * fr - c2i * fi, c2r * fi + c2i * fr);
  } else {
    // ---------------- W fp32 -> bf16 (once; consumed by k_out) ----------------
    const float4* __restrict__ W4 = (const float4*)W;
    ushort4* __restrict__ Wb4 = (ushort4*)w_bf;
#pragma unroll
    for (int m = 0; m < 16; ++m) {
      int idx = tid + 256 * m;  // [0,4096) float4s
      float4 w4 = W4[idx];
      ushort4 u;
      u.x = f2bf(w4.x); u.y = f2bf(w4.y); u.z = f2bf(w4.z); u.w = f2bf(w4.w);
      Wb4[idx] = u;
    }
  }
}

// ---------------------------------------------------------------------------
// Kernel 2: kf via even/odd-bin split. 512 threads/block, HW twiddles.
// ---------------------------------------------------------------------------
template <int Q, bool INV>
static __device__ __forceinline__ void kfs_dif(float2* s, int tid) {
  constexpr float SCR = (float)(2048 / (4 * Q)) * (1.0f / 2048.0f);  // revolutions
  int k = tid;  // [0,512)
  int j = k & (Q - 1);
  int i = ((k - j) << 2) + j;
  float2 w1 = INV ? twi((float)j * SCR) : twf((float)j * SCR);
  float2 a = s[PAD(i)], b = s[PAD(i + Q)], c2 = s[PAD(i + 2 * Q)], d = s[PAD(i + 3 * Q)];
  bf4g<INV>(a, b, c2, d, w1);
  s[PAD(i)] = a; s[PAD(i + Q)] = b; s[PAD(i + 2 * Q)] = c2; s[PAD(i + 3 * Q)] = d;
  __syncthreads();
}
template <int Q>
static __device__ __forceinline__ void kfs_dit(float2* s, int tid) {
  constexpr float SCR = (float)(2048 / (4 * Q)) * (1.0f / 2048.0f);
  int k = tid;
  int j = k & (Q - 1);
  int i = ((k - j) << 2) + j;
  float2 u1 = twf((float)j * SCR);
  float2 a = s[PAD(i)], b = s[PAD(i + Q)], c2 = s[PAD(i + 2 * Q)], d = s[PAD(i + 3 * Q)];
  bf4h<false>(a, b, c2, d, u1);
  s[PAD(i)] = a; s[PAD(i + Q)] = b; s[PAD(i + 2 * Q)] = c2; s[PAD(i + 3 * Q)] = d;
  __syncthreads();
}
static __device__ __forceinline__ void kfs_r2(float2* s, int tid) {
#pragma unroll
  for (int m = 0; m < 2; ++m) {
    int k = tid + 512 * m;  // [0,1024)
    int i = 2 * k;
    float2 a = s[PAD(i)], b = s[PAD(i + 1)];
    s[PAD(i)] = cadd(a, b);
    s[PAD(i + 1)] = csub(a, b);
  }
  __syncthreads();
}

__global__ __launch_bounds__(512) void k_kf(const float2* __restrict__ arr, float2* __restrict__ kf) {
  __shared__ float2 s[2176];
  const int tid = threadIdx.x;
  const int c = blockIdx.x;
  const float2* __restrict__ ac = arr + (size_t)c * 2048;
  float2* __restrict__ kfc = kf + (size_t)c * 4096;
#pragma unroll
  for (int m = 0; m < 4; ++m) {
    int q = tid + 512 * m;
    float2 aq = ac[q];
    s[PAD(q)] = aq;
    float2 am = ac[(2048 - q) & 2047];
    kfc[__brev((unsigned)q) >> 21] =
        make_float2((aq.x + am.x) * (0.5f / 4096.0f), (aq.y - am.y) * (0.5f / 4096.0f));
  }
  __syncthreads();
  kfs_dif<512, true>(s, tid);
  kfs_dif<128, true>(s, tid);
  kfs_dif<32, true>(s, tid);
  kfs_dif<8, true>(s, tid);
  kfs_dif<2, true>(s, tid);
  kfs_r2(s, tid);
#pragma unroll
  for (int m = 0; m < 4; ++m) {
    int p = tid + 512 * m;
    int t = (int)(__brev((unsigned)p) >> 21);
    float2 w = twf((float)t * (1.0f / 4096.0f));
    float kr = s[PAD(p)].x * (1.0f / 8388608.0f);
    s[PAD(p)] = make_float2(kr * w.x, kr * w.y);
  }
  __syncthreads();
  kfs_r2(s, tid);
  kfs_dit<2>(s, tid);
  kfs_dit<8>(s, tid);
  kfs_dit<32>(s, tid);
  kfs_dit<128>(s, tid);
  kfs_dit<512>(s, tid);
#pragma unroll
  for (int m = 0; m < 4; ++m) {
    int q = tid + 512 * m;
    kfc[2048 + (int)(__brev((unsigned)q) >> 21)] = s[PAD(q)];
  }
}

// ---------------------------------------------------------------------------
// Kernel 3: paired real FFT conv (y bf16), 3-level register FFT, HW twiddles;
// kf PREFETCHED into registers at kernel entry (strided L2 loads hidden under
// the forward FFT); s_setprio around the pure-register middle; D*y folded
// into spectrum; tanh-GELU; writes h as bf16 (B,C,T).
// ---------------------------------------------------------------------------
__global__ __launch_bounds__(256) void k_conv(const ushort_t* __restrict__ y_bf,
                                              const float2* __restrict__ kf,
                                              const float* __restrict__ D,
                                              ushort_t* __restrict__ h_bf) {
  __shared__ float2 s[4352];
  const int tid = threadIdx.x;
  const int p = blockIdx.x;
  const int b = p >> 7, c = p & 127;
  const ushort_t* __restrict__ r1 = y_bf + (size_t)(b * 128 + c) * 2048;
  const ushort_t* __restrict__ r2 = y_bf + (size_t)((b + 8) * 128 + c) * 2048;
  ushort_t* __restrict__ hb1 = h_bf + (size_t)(b * 128 + c) * 2048;
  ushort_t* __restrict__ hb2 = h_bf + (size_t)((b + 8) * 128 + c) * 2048;

  const float2 K1 = make_float2(W256R, W256I);
  const float2 K2 = make_float2(W512R, W512I);
  const float2 K3 = make_float2(W768R, W768I);

  // ---- prefetch kf + D at entry: latency hides under the forward FFT ----
  float2 kreg[16];
  {
    const float2* __restrict__ kfc = kf + (size_t)c * 4096 + 16 * tid;
#pragma unroll
    for (int e = 0; e < 16; ++e) kreg[e] = kfc[e];
  }
  const float Dc = D[c];

  float2 v[16];
  // ---- forward phase A: Q=1024 (legs 2,3 zero), Q=256 ----
  {
    float2 ya[8];
#pragma unroll
    for (int e = 0; e < 8; ++e)
      ya[e] = make_float2(bf2f(r1[tid + 256 * e]), bf2f(r2[tid + 256 * e]));
    const float2 wt = twf((float)tid * (1.0f / 4096.0f));
    bf4f_z(ya[0], ya[4], wt,            v[0], v[4], v[8], v[12]);
    bf4f_z(ya[1], ya[5], cmulf(wt, K1), v[1], v[5], v[9], v[13]);
    bf4f_z(ya[2], ya[6], cmulf(wt, K2), v[2], v[6], v[10], v[14]);
    bf4f_z(ya[3], ya[7], cmulf(wt, K3), v[3], v[7], v[11], v[15]);
  }
  {
    const float2 wq = twf((float)tid * (1.0f / 1024.0f));
    const float2 wq2 = cmulf(wq, wq), wq3 = cmulf(wq2, wq);
    bf4f3(v[0], v[1], v[2], v[3], wq, wq2, wq3);
    bf4f3(v[4], v[5], v[6], v[7], wq, wq2, wq3);
    bf4f3(v[8], v[9], v[10], v[11], wq, wq2, wq3);
    bf4f3(v[12], v[13], v[14], v[15], wq, wq2, wq3);
  }
  // ---- exchange 1: write A-pattern, read B-pattern ----
  {
    const int wb0 = tid + (tid >> 4);
#pragma unroll
    for (int e = 0; e < 16; ++e) s[272 * e + wb0] = v[e];
  }
  __syncthreads();
  const int a_ = tid >> 4, b_ = tid & 15;
  const int rbB = 272 * a_ + b_;
#pragma unroll
  for (int e = 0; e < 16; ++e) v[e] = s[rbB + 17 * e];
  // ---- forward phase B: Q=64, Q=16 ----
  {
    const float2 wb = twf((float)b_ * (1.0f / 256.0f));
    bf4f(v[0], v[4], v[8], v[12], wb);
    bf4f(v[1], v[5], v[9], v[13], cmulf(wb, K1));
    bf4f(v[2], v[6], v[10], v[14], cmulf(wb, K2));
    bf4f(v[3], v[7], v[11], v[15], cmulf(wb, K3));
  }
  {
    const float2 w16 = twf((float)b_ * (1.0f / 64.0f));
    const float2 w162 = cmulf(w16, w16), w163 = cmulf(w162, w16);
    bf4f3(v[0], v[1], v[2], v[3], w16, w162, w163);
    bf4f3(v[4], v[5], v[6], v[7], w16, w162, w163);
    bf4f3(v[8], v[9], v[10], v[11], w16, w162, w163);
    bf4f3(v[12], v[13], v[14], v[15], w16, w162, w163);
  }
  // ---- exchange 2 ----
#pragma unroll
  for (int e = 0; e < 16; ++e) s[rbB + 17 * e] = v[e];
  __syncthreads();
#pragma unroll
  for (int e = 0; e < 16; ++e) v[e] = s[17 * tid + e];
  // ---- pure-register middle: fwd phase C, multiply, inv phase C ----
  __builtin_amdgcn_s_setprio(1);
  bf4f1(v[0], v[4], v[8], v[12]);
  bf4f(v[1], v[5], v[9], v[13], K1);
  bf4f(v[2], v[6], v[10], v[14], K2);
  bf4f(v[3], v[7], v[11], v[15], K3);
  bf4f1(v[0], v[1], v[2], v[3]);
  bf4f1(v[4], v[5], v[6], v[7]);
  bf4f1(v[8], v[9], v[10], v[11]);
  bf4f1(v[12], v[13], v[14], v[15]);
  // spectral multiply with (K + D) (kf pre-scaled by 1/4096, prefetched)
  {
    const float dsc = Dc * (1.0f / 4096.0f);
#pragma unroll
    for (int e = 0; e < 16; ++e) {
      float2 kv = kreg[e];
      kv.x += dsc;
      v[e] = cmulf(v[e], kv);
    }
  }
  bf4i1(v[0], v[1], v[2], v[3]);
  bf4i1(v[4], v[5], v[6], v[7]);
  bf4i1(v[8], v[9], v[10], v[11]);
  bf4i1(v[12], v[13], v[14], v[15]);
  bf4i1(v[0], v[4], v[8], v[12]);
  bf4i(v[1], v[5], v[9], v[13], cconj(K1));
  bf4i(v[2], v[6], v[10], v[14], cconj(K2));
  bf4i(v[3], v[7], v[11], v[15], cconj(K3));
  __builtin_amdgcn_s_setprio(0);
  // ---- exchange 3 ----
#pragma unroll
  for (int e = 0; e < 16; ++e) s[17 * tid + e] = v[e];
  __syncthreads();
#pragma unroll
  for (int e = 0; e < 16; ++e) v[e] = s[rbB + 17 * e];
  // ---- inverse phase B ----
  {
    const float2 w16c = twi((float)b_ * (1.0f / 64.0f));
    const float2 w16c2 = cmulf(w16c, w16c);
    bf4i3(v[0], v[1], v[2], v[3], w16c, w16c2);
    bf4i3(v[4], v[5], v[6], v[7], w16c, w16c2);
    bf4i3(v[8], v[9], v[10], v[11], w16c, w16c2);
    bf4i3(v[12], v[13], v[14], v[15], w16c, w16c2);
  }
  {
    const float2 wbc = twi((float)b_ * (1.0f / 256.0f));
    bf4i(v[0], v[4], v[8], v[12], wbc);
    bf4i(v[1], v[5], v[9], v[13], cmulf(wbc, cconj(K1)));
    bf4i(v[2], v[6], v[10], v[14], cmulf(wbc, cconj(K2)));
    bf4i(v[3], v[7], v[11], v[15], cmulf(wbc, cconj(K3)));
  }
  // ---- exchange 4 ----
#pragma unroll
  for (int e = 0; e < 16; ++e) s[rbB + 17 * e] = v[e];
  __syncthreads();
  {
    const int wb0 = tid + (tid >> 4);
#pragma unroll
    for (int e = 0; e < 16; ++e) v[e] = s[272 * e + wb0];
  }
  // ---- inverse phase A: Q=256, then Q=1024 fused with GELU + bf16 store ----
  {
    const float2 wqc = twi((float)tid * (1.0f / 1024.0f));
    const float2 wqc2 = cmulf(wqc, wqc);
    bf4i3(v[0], v[1], v[2], v[3], wqc, wqc2);
    bf4i3(v[4], v[5], v[6], v[7], wqc, wqc2);
    bf4i3(v[8], v[9], v[10], v[11], wqc, wqc2);
    bf4i3(v[12], v[13], v[14], v[15], wqc, wqc2);
  }
  const float2 wtc = twi((float)tid * (1.0f / 4096.0f));
  auto fin = [&](float2 va, float2 vb, float2 vc2, float2 vd, float2 u1, int e0) {
    float2 u2 = cmulf(u1, u1);
    float2 tb = cmulf(vb, u2), td = cmulf(vd, u2);
    float2 a1 = cadd(va, tb), b1 = csub(va, tb), c1 = cadd(vc2, td), d1 = csub(vc2, td);
    float2 tc = cmulf(c1, u1), te = cmulf(d1, u1);
    float2 oa = cadd(a1, tc);
    float2 ob = make_float2(b1.x - te.y, b1.y + te.x);
    int i0 = tid + 256 * e0;
    hb1[i0] = f2bf(gelu1(oa.x));
    hb2[i0] = f2bf(gelu1(oa.y));
    hb1[i0 + 1024] = f2bf(gelu1(ob.x));
    hb2[i0 + 1024] = f2bf(gelu1(ob.y));
  };
  fin(v[0], v[4], v[8], v[12], wtc, 0);
  fin(v[1], v[5], v[9], v[13], cmulf(wtc, cconj(K1)), 1);
  fin(v[2], v[6], v[10], v[14], cmulf(wtc, cconj(K2)), 2);
  fin(v[3], v[7], v[11], v[15], cmulf(wtc, cconj(K3)), 3);
}

// ---------------------------------------------------------------------------
// Kernel 4 (MFMA bf16): out[b,t,o] = sum_c h[b,c,t]*W[o,c] + b_out[o] + x[b,t,o]
// W staged from pre-converted bf16 (w_bf, written by k_ln_ar block 2048).
// ---------------------------------------------------------------------------
__global__ __launch_bounds__(256) void k_out(const ushort_t* __restrict__ h_bf,
                                             const ushort_t* __restrict__ w_bf,
                                             const float* __restrict__ bout,
                                             const float* __restrict__ x,
                                             float* __restrict__ out) {
  __shared__ __align__(16) char smem[52224];
  ushort_t* Wl = (ushort_t*)smem;                  // [128][136]
  ushort_t* hl = (ushort_t*)(smem + 34816);        // [64][136]
  const int tid = threadIdx.x;
  const int b = blockIdx.x >> 5;
  const int t0 = (blockIdx.x & 31) << 6;

  // stage W (bf16, swizzled: col' = ((cb ^ (o&15))<<3) + (c&7))
  {
    const ushort4* __restrict__ Wb4 = (const ushort4*)w_bf;
#pragma unroll
    for (int r = 0; r < 16; ++r) {
      int idx = tid + 256 * r;  // 128 o x 32 j
      int o = idx >> 5, j = idx & 31;
      ushort4 u = Wb4[o * 32 + j];
      int sc = (((j >> 1) ^ (o & 15)) << 3) + 4 * (j & 1);
      *(ushort4*)&Wl[o * 136 + sc] = u;
    }
  }
  // stage h tile (bf16 global (b,c,t) -> LDS [t][c] swizzled)
  {
#pragma unroll
    for (int r = 0; r < 8; ++r) {
      int idx = tid + 256 * r;  // 128 c x 16 t4
      int cc = idx >> 4, t4 = (idx & 15) * 4;
      ushort4 hv = *(const ushort4*)&h_bf[((size_t)(b * 128 + cc)) * 2048 + t0 + t4];
      int cb = cc >> 3, clo = cc & 7;
#pragma unroll
      for (int i = 0; i < 4; ++i) {
        int t = t4 + i;
        hl[t * 136 + (((cb ^ (t & 15)) << 3) + clo)] = ((const ushort_t*)&hv)[i];
      }
    }
  }
  __syncthreads();

  const int l = tid & 63;
  const int w = tid >> 6;
  const int tl = l & 15;
  const int g = l >> 4;
  f32x4 acc[8];
#pragma unroll
  for (int i = 0; i < 8; ++i) acc[i] = (f32x4){0.f, 0.f, 0.f, 0.f};

#pragma unroll
  for (int ks = 0; ks < 4; ++ks) {
    int cb = ks * 4 + g;
    int col = ((cb ^ tl) << 3);
    bf16x8 bfrag = *(const bf16x8*)&hl[(16 * w + tl) * 136 + col];
#pragma unroll
    for (int ot = 0; ot < 8; ++ot) {
      bf16x8 afrag = *(const bf16x8*)&Wl[(ot * 16 + tl) * 136 + col];
      acc[ot] = __builtin_amdgcn_mfma_f32_16x16x32_bf16(afrag, bfrag, acc[ot], 0, 0, 0);
    }
  }
  // direct epilogue: acc[ot][r] = out[o=16ot+4g+r][t=16w+tl]
  const int t = t0 + 16 * w + tl;
  const size_t rowoff = ((size_t)b * 2048 + t) * 128;
#pragma unroll
  for (int ot = 0; ot < 8; ++ot) {
    int o = ot * 16 + g * 4;
    float4 xv = *(const float4*)&x[rowoff + o];
    float4 bo4 = *(const float4*)&bout[o];
    float4 v;
    v.x = acc[ot][0] + bo4.x + xv.x;
    v.y = acc[ot][1] + bo4.y + xv.y;
    v.z = acc[ot][2] + bo4.z + xv.z;
    v.w = acc[ot][3] + bo4.w + xv.w;
    *(float4*)&out[rowoff + o] = v;
  }
}

// ---------------------------------------------------------------------------

extern "C" void kernel_launch(void* const* d_in, const int* in_sizes, int n_in,
                              void* d_out, int out_size, void* d_ws, size_t ws_size,
                              hipStream_t stream) {
  (void)in_sizes; (void)n_in; (void)out_size; (void)ws_size;
  const float* x  = (const float*)d_in[0];
  const float* g  = (const float*)d_in[1];
  const float* be = (const float*)d_in[2];
  const float* Lr = (const float*)d_in[3];
  const float* Li = (const float*)d_in[4];
  const float* Pr = (const float*)d_in[5];
  const float* Pi = (const float*)d_in[6];
  const float* Br = (const float*)d_in[7];
  const float* Bi = (const float*)d_in[8];
  const float* Cr = (const float*)d_in[9];
  const float* Ci = (const float*)d_in[10];
  const float* D  = (const float*)d_in[11];
  const float* W  = (const float*)d_in[12];
  const float* bo = (const float*)d_in[13];
  float* out = (float*)d_out;

  char* ws = (char*)d_ws;
  ushort_t* y_bf = (ushort_t*)ws;                 //  8 MiB: y bf16 (B,C,T)
  float2*   arr  = (float2*)(ws + (16u << 20));   //  2 MiB: at_roots (C,L)
  float2*   kfb  = (float2*)(ws + (18u << 20));   //  4 MiB: kernel spectrum
  ushort_t* h_bf = (ushort_t*)(ws + (22u << 20)); //  8 MiB: h bf16 (B,C,T)
  ushort_t* w_bf = (ushort_t*)(ws + (30u << 20)); // 32 KiB: W bf16

  hipLaunchKernelGGL(k_ln_ar, dim3(2049), dim3(256), 0, stream,
                     x, g, be, y_bf, Lr, Li, Pr, Pi, Br, Bi, Cr, Ci, arr, W, w_bf);
  hipLaunchKernelGGL(k_kf,   dim3(128),  dim3(512), 0, stream, arr, kfb);
  hipLaunchKernelGGL(k_conv, dim3(1024), dim3(256), 0, stream, y_bf, kfb, D, h_bf);
  hipLaunchKernelGGL(k_out,  dim3(512),  dim3(256), 0, stream, h_bf, w_bf, bo, x, out);
}